// Round 5
// baseline (18552.597 us; speedup 1.0000x reference)
//
#include <hip/hip_runtime.h>
#include <math.h>

#define NN 4096
#define TT 64
#define HH 128
#define SPLITS 16
#define KPB (NN / SPLITS)    // 256 keys per block
#define KT 32                // key tile
#define NTILES (KPB / KT)    // 8
#define NBLK 512
#define SCALE 0.08838834764831845f    // 1/sqrt(128)
#define CSHIFT 16.0f
#define SPIN_CAP 300000

typedef __attribute__((ext_vector_type(8))) short short8;
typedef __attribute__((ext_vector_type(4))) short short4b;
typedef __attribute__((ext_vector_type(4))) float f32x4;
#define MFMA(a, b, c) __builtin_amdgcn_mfma_f32_16x16x32_bf16((a), (b), (c), 0, 0, 0)

// ---- bf16 helpers (RNE) ----
__device__ __forceinline__ short f2b(float f) {
    union { float f; unsigned u; } v; v.f = f;
    unsigned r = v.u + 0x7fffu + ((v.u >> 16) & 1u);
    return (short)(r >> 16);
}
__device__ __forceinline__ float b2f(short s) {
    union { unsigned u; float f; } v; v.u = ((unsigned)(unsigned short)s) << 16;
    return v.f;
}
// 8-byte-aligned short8 load (two ds_read_b64) for stride-36 Pt rows
__device__ __forceinline__ short8 load_s8_a8(const short* p) {
    short4b lo = *(const short4b*)p;
    short4b hi = *(const short4b*)(p + 4);
    short8 r;
    r[0] = lo[0]; r[1] = lo[1]; r[2] = lo[2]; r[3] = lo[3];
    r[4] = hi[0]; r[5] = hi[1]; r[6] = hi[2]; r[7] = hi[3];
    return r;
}

// ===========================================================================
// prep: once per launch. bf16 weight transposes; hp0 = b_proj (h0=0);
// hin0/hinT0 from x[:,0], m[:,0].
// ===========================================================================
__global__ __launch_bounds__(256) void prep_kernel(
    const float* __restrict__ x_seq, const float* __restrict__ m_seq,
    const float* __restrict__ W_in,  const float* __restrict__ b_in,
    const float* __restrict__ W_proj,const float* __restrict__ b_proj,
    const float* __restrict__ W_gcn,
    short* __restrict__ hp0, short* __restrict__ hin0, short* __restrict__ hinT0,
    short* __restrict__ WgT, short* __restrict__ WpT)
{
    const int b = blockIdx.x, tid = threadIdx.x;
    if (b < 256) {
        const int n0 = b * 16;
        for (int i = tid; i < 16 * HH; i += 256) {
            const int q = i >> 7, j = i & 127, n = n0 + q;
            hp0[n * HH + j] = f2b(b_proj[j]);
            float hi = x_seq[n * TT] * W_in[j] + m_seq[n * TT] * W_in[HH + j] + b_in[j];
            hi = hi > 0.f ? hi : 0.f;
            const short hb = f2b(hi);
            hin0[n * HH + j] = hb;
            hinT0[j * NN + n] = hb;
        }
    } else {
        const int wb = b - 256;
        #pragma unroll
        for (int k = 0; k < 4; ++k) {
            const int idx = wb * 1024 + k * 256 + tid;   // = n*128 + kk
            const int n = idx >> 7, kk = idx & 127;
            WgT[idx] = f2b(W_gcn[kk * HH + n]);
            WpT[idx] = f2b(W_proj[kk * HH + n]);
        }
    }
}

// ===========================================================================
// Persistent kernel: all 64 timesteps. 512 blocks x 256 thr (4 waves).
// Block = (qg: 128 q rows) x (split: 256 keys). Per step:
//   phase A: attention partials (round-4 body; Pt stride 36 = b16 floor)
//   election: 16th finisher of each qg merges+fuses its 128 rows
//   grid barrier: per-step counter, relaxed poll + threadfence acq/rel
// hp/hin/hinT are ping-ponged on t parity -> no WAR with in-flight readers.
// LDS pool 47KB: merge arrays alias Kt (phase A complete at that point).
// ===========================================================================
__global__ __launch_bounds__(256, 2) void persist_kernel(
    short* __restrict__ hp0, short* __restrict__ hp1,
    short* __restrict__ hin0, short* __restrict__ hin1,
    short* __restrict__ hinT0, short* __restrict__ hinT1,
    const short* __restrict__ WgT, const short* __restrict__ WpT,
    const float* __restrict__ b_gcn, const float* __restrict__ b_proj,
    const float* __restrict__ W_out, const float* __restrict__ b_out,
    const float* __restrict__ x_seq, const float* __restrict__ m_seq,
    const float* __restrict__ W_in,  const float* __restrict__ b_in,
    float* __restrict__ Opart, float* __restrict__ lpart,
    int* __restrict__ mcnt, int* __restrict__ bcnt,
    float* __restrict__ out)
{
    __shared__ __align__(16) char pool[47104];
    __shared__ int winflag;
    short* KtP = (short*)pool;              // [2][32*136]  (17408 B)
    short* VtP = (short*)(pool + 17408);    // [2][128*40]  (20480 B)
    short* PtP = (short*)(pool + 37888);    // [4][32*36]   (9216 B)

    const int tid  = threadIdx.x;
    const int wave = tid >> 6, lane = tid & 63;
    const int ln = lane & 15, g = lane >> 4;
    const int qg = blockIdx.x >> 4, split = blockIdx.x & 15;
    const int q0 = qg * 128 + wave * 32;
    const int kbase = split * KPB;

    // staging thread map (whole block cooperates)
    const int krow = tid >> 3, kcol = (tid & 7) * 16;   // 32 rows x 128 shorts
    const int vrow = tid >> 1, vcol = (tid & 1) * 16;   // 128 rows x 32 shorts

    for (int t = 0; t < TT; ++t) {
        const short* hpR   = (t & 1) ? hp1   : hp0;
        short*       hpW   = (t & 1) ? hp0   : hp1;
        const short* hinR  = (t & 1) ? hin1  : hin0;
        short*       hinW  = (t & 1) ? hin0  : hin1;
        const short* hinTR = (t & 1) ? hinT1 : hinT0;
        short*       hinTW = (t & 1) ? hinT0 : hinT1;

        // ================= phase A: attention partials =================
        short8 qf[2][4];
        #pragma unroll
        for (int mt = 0; mt < 2; ++mt)
            #pragma unroll
            for (int kc = 0; kc < 4; ++kc)
                qf[mt][kc] = *(const short8*)&hpR[(q0 + mt * 16 + ln) * HH + kc * 32 + g * 8];

        f32x4 oacc[2][8] = {};
        float lsum[2][4] = {};
        short8 ksA, ksB, vsA, vsB;

        auto load_tile = [&](int kt_) {
            const int kb = kbase + kt_ * KT;
            ksA = *(const short8*)&hpR  [(kb + krow) * HH + kcol];
            ksB = *(const short8*)&hpR  [(kb + krow) * HH + kcol + 8];
            vsA = *(const short8*)&hinTR[(size_t)vrow * NN + kb + vcol];
            vsB = *(const short8*)&hinTR[(size_t)vrow * NN + kb + vcol + 8];
        };
        auto store_tile = [&](int b) {
            *(short8*)&KtP[b * 4352 + krow * 136 + kcol]     = ksA;
            *(short8*)&KtP[b * 4352 + krow * 136 + kcol + 8] = ksB;
            *(short8*)&VtP[b * 5120 + vrow * 40 + vcol]      = vsA;
            *(short8*)&VtP[b * 5120 + vrow * 40 + vcol + 8]  = vsB;
        };

        load_tile(0);
        store_tile(0);

        for (int kt = 0; kt < NTILES; ++kt) {
            const int b = kt & 1;
            __syncthreads();   // buf b staged; prev iter's LDS reads done

            short8 kf[2][4], vf[8];
            #pragma unroll
            for (int nt = 0; nt < 2; ++nt)
                #pragma unroll
                for (int kc = 0; kc < 4; ++kc)
                    kf[nt][kc] = *(const short8*)&KtP[b * 4352 + (nt * 16 + ln) * 136 + kc * 32 + g * 8];
            #pragma unroll
            for (int dt = 0; dt < 8; ++dt)
                vf[dt] = *(const short8*)&VtP[b * 5120 + (dt * 16 + ln) * 40 + g * 8];

            if (kt + 1 < NTILES) load_tile(kt + 1);

            f32x4 sacc[2][2] = {};
            #pragma unroll
            for (int mt = 0; mt < 2; ++mt)
                #pragma unroll
                for (int nt = 0; nt < 2; ++nt)
                    #pragma unroll
                    for (int kc = 0; kc < 4; ++kc)
                        sacc[mt][nt] = MFMA(qf[mt][kc], kf[nt][kc], sacc[mt][nt]);

            // fixed-shift softmax numerators -> Pt (stride 36: 2 lanes/bank)
            #pragma unroll
            for (int mt = 0; mt < 2; ++mt)
                #pragma unroll
                for (int nt = 0; nt < 2; ++nt)
                    #pragma unroll
                    for (int r = 0; r < 4; ++r) {
                        const float p = __expf(sacc[mt][nt][r] * SCALE - CSHIFT);
                        const short pb = f2b(p);
                        lsum[mt][r] += b2f(pb);
                        PtP[wave * 1152 + (mt * 16 + g * 4 + r) * 36 + nt * 16 + ln] = pb;
                    }

            if (kt + 1 < NTILES) store_tile(b ^ 1);

            __syncthreads();   // Pt RAW fence (round-2 lesson: mandatory)

            short8 pf0 = load_s8_a8(&PtP[wave * 1152 + ln * 36 + g * 8]);
            short8 pf1 = load_s8_a8(&PtP[wave * 1152 + (16 + ln) * 36 + g * 8]);

            #pragma unroll
            for (int dt = 0; dt < 8; ++dt) {
                oacc[0][dt] = MFMA(pf0, vf[dt], oacc[0][dt]);
                oacc[1][dt] = MFMA(pf1, vf[dt], oacc[1][dt]);
            }
        }

        // l reduction over 16-lane key dim; partial writes
        #pragma unroll
        for (int mt = 0; mt < 2; ++mt)
            #pragma unroll
            for (int r = 0; r < 4; ++r) {
                float l = lsum[mt][r];
                l += __shfl_xor(l, 1); l += __shfl_xor(l, 2);
                l += __shfl_xor(l, 4); l += __shfl_xor(l, 8);
                if (ln == 0) lpart[split * NN + q0 + mt * 16 + g * 4 + r] = l;
            }
        #pragma unroll
        for (int mt = 0; mt < 2; ++mt)
            #pragma unroll
            for (int dt = 0; dt < 8; ++dt)
                #pragma unroll
                for (int r = 0; r < 4; ++r)
                    Opart[((size_t)split * NN + q0 + mt * 16 + g * 4 + r) * HH + dt * 16 + ln] = oacc[mt][dt][r];

        // ================= election =================
        __syncthreads();        // all waves' partial stores drained (vmcnt)
        __threadfence();        // release partials to device scope
        if (tid == 0) {
            int old = atomicAdd(&mcnt[t * 32 + qg], 1);
            winflag = (old == SPLITS - 1);
        }
        __syncthreads();

        if (winflag) {
            __threadfence();    // acquire all splits' partials (cross-XCD)

            // merge+fuse 128 q rows: 2 teams (2 waves each) x 4 subtiles
            const int team  = wave >> 1;
            const int twave = wave & 1;
            const int ttid  = twave * 64 + lane;
            short* msgb = (short*)pool + team * 2176;            // 16*136 shorts, alias Kt
            short* hnb  = (short*)pool + 4352 + team * 2176;     // alias Kt
            float* larr = (float*)(pool + 37888) + team * 16;    // alias Pt
            float* ppdT = (float*)(pool + 37888 + 128) + team * 32;

            for (int st = 0; st < 4; ++st) {
                const int qb = qg * 128 + (team * 4 + st) * 16;

                if (ttid < 16) {
                    float l = 0.f;
                    #pragma unroll
                    for (int sp = 0; sp < SPLITS; ++sp) l += lpart[sp * NN + qb + ttid];
                    larr[ttid] = 1.0f / l;
                }
                __syncthreads();

                for (int i = ttid; i < 16 * 32; i += 128) {
                    const int q = i >> 5, d4 = (i & 31) * 4;
                    f32x4 s = {};
                    #pragma unroll
                    for (int sp = 0; sp < SPLITS; ++sp)
                        s += *(const f32x4*)&Opart[((size_t)sp * NN + qb + q) * HH + d4];
                    const float inv = larr[q];
                    short4b mv = { f2b(s[0] * inv), f2b(s[1] * inv), f2b(s[2] * inv), f2b(s[3] * inv) };
                    *(short4b*)&msgb[q * 136 + d4] = mv;
                }
                __syncthreads();

                // GEMM1: h_new = relu(msg @ W_gcn + b_gcn + h_in); pred partials
                short8 af[4];
                #pragma unroll
                for (int kc = 0; kc < 4; ++kc)
                    af[kc] = *(const short8*)&msgb[ln * 136 + kc * 32 + g * 8];
                float pr[4] = {0.f, 0.f, 0.f, 0.f};
                #pragma unroll
                for (int ni = 0; ni < 4; ++ni) {
                    const int nt = twave * 4 + ni;
                    f32x4 c = {};
                    #pragma unroll
                    for (int kc = 0; kc < 4; ++kc)
                        c = MFMA(af[kc], *(const short8*)&WgT[(nt * 16 + ln) * HH + kc * 32 + g * 8], c);
                    const float bg = b_gcn[nt * 16 + ln];
                    const float wo = W_out[nt * 16 + ln];
                    #pragma unroll
                    for (int r = 0; r < 4; ++r) {
                        const int q = g * 4 + r;
                        float v = c[r] + bg + b2f(hinR[(qb + q) * HH + nt * 16 + ln]);
                        v = v > 0.f ? v : 0.f;
                        hnb[q * 136 + nt * 16 + ln] = f2b(v);
                        pr[r] += v * wo;
                    }
                }
                #pragma unroll
                for (int r = 0; r < 4; ++r) {
                    float p = pr[r];
                    p += __shfl_xor(p, 1); p += __shfl_xor(p, 2);
                    p += __shfl_xor(p, 4); p += __shfl_xor(p, 8);
                    if (ln == 0) ppdT[twave * 16 + g * 4 + r] = p;
                }
                __syncthreads();

                if (ttid < 16) out[(qb + ttid) * TT + t] = ppdT[ttid] + ppdT[16 + ttid] + b_out[0];

                // GEMM2: h_proj(t+1) = h_new @ W_proj + b_proj
                short8 hf[4];
                #pragma unroll
                for (int kc = 0; kc < 4; ++kc)
                    hf[kc] = *(const short8*)&hnb[ln * 136 + kc * 32 + g * 8];
                #pragma unroll
                for (int ni = 0; ni < 4; ++ni) {
                    const int nt = twave * 4 + ni;
                    f32x4 c = {};
                    #pragma unroll
                    for (int kc = 0; kc < 4; ++kc)
                        c = MFMA(hf[kc], *(const short8*)&WpT[(nt * 16 + ln) * HH + kc * 32 + g * 8], c);
                    const float bp = b_proj[nt * 16 + ln];
                    #pragma unroll
                    for (int r = 0; r < 4; ++r)
                        hpW[(qb + g * 4 + r) * HH + nt * 16 + ln] = f2b(c[r] + bp);
                }

                // h_in(t+1)
                if (t < TT - 1) {
                    for (int i = ttid; i < 16 * HH; i += 128) {
                        const int q = i >> 7, j = i & 127;
                        float hi = x_seq[(qb + q) * TT + t + 1] * W_in[j]
                                 + m_seq[(qb + q) * TT + t + 1] * W_in[HH + j] + b_in[j];
                        hi = hi > 0.f ? hi : 0.f;
                        const short hb = f2b(hi);
                        hinW[(qb + q) * HH + j] = hb;
                        hinTW[(size_t)j * NN + qb + q] = hb;
                    }
                }
                __syncthreads();
            }
            __syncthreads();    // fuse stores drained
            __threadfence();    // release hp/hin/hinT (t+1) to device scope
        }

        // ================= grid barrier =================
        if (tid == 0) {
            atomicAdd(&bcnt[t], 1);
            int it = 0;
            while (__hip_atomic_load(&bcnt[t], __ATOMIC_RELAXED, __HIP_MEMORY_SCOPE_AGENT) < NBLK
                   && it < SPIN_CAP) { ++it; __builtin_amdgcn_s_sleep(2); }
        }
        __syncthreads();
        __threadfence();        // acquire next-step state (invalidate stale L2)
    }
}

// ===========================================================================
extern "C" void kernel_launch(void* const* d_in, const int* in_sizes, int n_in,
                              void* d_out, int out_size, void* d_ws, size_t ws_size,
                              hipStream_t stream) {
    const float* x_seq  = (const float*)d_in[0];
    const float* m_seq  = (const float*)d_in[1];
    const float* W_in   = (const float*)d_in[2];
    const float* b_in   = (const float*)d_in[3];
    const float* W_proj = (const float*)d_in[4];
    const float* b_proj = (const float*)d_in[5];
    const float* W_gcn  = (const float*)d_in[6];
    const float* b_gcn  = (const float*)d_in[7];
    const float* W_out  = (const float*)d_in[8];
    const float* b_out  = (const float*)d_in[9];
    float* out = (float*)d_out;

    // ws carve (~40 MB): hp x2 | hin x2 | hinT x2 | WgT | WpT | lpart | ctrl | Opart
    char* base = (char*)d_ws;
    const size_t MB = 1 << 20;
    short* hp0   = (short*)(base + 0 * MB);
    short* hp1   = (short*)(base + 1 * MB);
    short* hin0  = (short*)(base + 2 * MB);
    short* hin1  = (short*)(base + 3 * MB);
    short* hinT0 = (short*)(base + 4 * MB);
    short* hinT1 = (short*)(base + 5 * MB);
    short* WgT   = (short*)(base + 6 * MB);
    short* WpT   = (short*)(base + 6 * MB + 32768);
    float* lpart = (float*)(base + 6 * MB + 65536);            // 256 KB
    int*   ctrl  = (int*)  (base + 6 * MB + 65536 + 262144);   // mcnt[2048] + bcnt[64]
    int*   mcnt  = ctrl;
    int*   bcnt  = ctrl + 2048;
    float* Opart = (float*)(base + 8 * MB);                    // 32 MB

    hipMemsetAsync(ctrl, 0, (2048 + 64) * sizeof(int), stream);
    prep_kernel<<<272, 256, 0, stream>>>(x_seq, m_seq, W_in, b_in, W_proj, b_proj,
                                         W_gcn, hp0, hin0, hinT0, WgT, WpT);
    persist_kernel<<<NBLK, 256, 0, stream>>>(hp0, hp1, hin0, hin1, hinT0, hinT1,
                                             WgT, WpT, b_gcn, b_proj, W_out, b_out,
                                             x_seq, m_seq, W_in, b_in,
                                             Opart, lpart, mcnt, bcnt, out);
}

// Round 6
// 16267.513 us; speedup vs baseline: 1.1405x; 1.1405x over previous
//
#include <hip/hip_runtime.h>
#include <math.h>

#define NN 4096
#define TT 64
#define HH 128
#define SPLITS 16
#define KPB (NN / SPLITS)    // 256 keys per block
#define KT 32                // key tile
#define NTILES (KPB / KT)    // 8
#define NBLK 512
#define NSIG (NBLK * 4)      // barrier signals: one per wave
#define SCALE 0.08838834764831845f    // 1/sqrt(128)
#define CSHIFT 16.0f
#define SPIN_CAP 200000
#define AGENT __HIP_MEMORY_SCOPE_AGENT

typedef __attribute__((ext_vector_type(8))) short short8;
typedef __attribute__((ext_vector_type(4))) float f32x4;
typedef unsigned long long u64;
#define MFMA(a, b, c) __builtin_amdgcn_mfma_f32_16x16x32_bf16((a), (b), (c), 0, 0, 0)

// ---- bf16 helpers (RNE) ----
__device__ __forceinline__ short f2b(float f) {
    union { float f; unsigned u; } v; v.f = f;
    unsigned r = v.u + 0x7fffu + ((v.u >> 16) & 1u);
    return (short)(r >> 16);
}
__device__ __forceinline__ float b2f(short s) {
    union { unsigned u; float f; } v; v.u = ((unsigned)(unsigned short)s) << 16;
    return v.f;
}

// ---- agent-scope (sc1 / LLC-coherent) access helpers. These bypass the
// non-coherent per-XCD L2, so cross-block visibility needs NO cache
// invalidates (round-5 lesson: __threadfence's L2 invalidate destroyed all
// K/V L2 reuse -> 66 MB/step from HBM). ----
__device__ __forceinline__ short8 ldg_sc(const short* p) {
    union { u64 u[2]; short8 v; } r;
    r.u[0] = __hip_atomic_load((const u64*)p,       __ATOMIC_RELAXED, AGENT);
    r.u[1] = __hip_atomic_load((const u64*)(p + 4), __ATOMIC_RELAXED, AGENT);
    return r.v;
}
__device__ __forceinline__ f32x4 ldg_sc_f4(const float* p) {
    union { u64 u[2]; f32x4 v; } r;
    r.u[0] = __hip_atomic_load((const u64*)p,       __ATOMIC_RELAXED, AGENT);
    r.u[1] = __hip_atomic_load((const u64*)(p + 2), __ATOMIC_RELAXED, AGENT);
    return r.v;
}
__device__ __forceinline__ void stg_sc8(short* p, u64 v) {
    __hip_atomic_store((u64*)p, v, __ATOMIC_RELAXED, AGENT);
}
__device__ __forceinline__ void stg_sc_f(float* p, float v) {
    __hip_atomic_store(p, v, __ATOMIC_RELAXED, AGENT);
}

// ===========================================================================
// prep: once per launch (normal stores; kernel-end release publishes them).
// ===========================================================================
__global__ __launch_bounds__(256) void prep_kernel(
    const float* __restrict__ x_seq, const float* __restrict__ m_seq,
    const float* __restrict__ W_in,  const float* __restrict__ b_in,
    const float* __restrict__ W_proj,const float* __restrict__ b_proj,
    const float* __restrict__ W_gcn,
    short* __restrict__ hp0, short* __restrict__ hin0, short* __restrict__ hinT0,
    short* __restrict__ WgT, short* __restrict__ WpT)
{
    const int b = blockIdx.x, tid = threadIdx.x;
    if (b < 256) {
        const int n0 = b * 16;
        for (int i = tid; i < 16 * HH; i += 256) {
            const int q = i >> 7, j = i & 127, n = n0 + q;
            hp0[n * HH + j] = f2b(b_proj[j]);
            float hi = x_seq[n * TT] * W_in[j] + m_seq[n * TT] * W_in[HH + j] + b_in[j];
            hi = hi > 0.f ? hi : 0.f;
            const short hb = f2b(hi);
            hin0[n * HH + j] = hb;
            hinT0[j * NN + n] = hb;
        }
    } else {
        const int wb = b - 256;
        #pragma unroll
        for (int k = 0; k < 4; ++k) {
            const int idx = wb * 1024 + k * 256 + tid;   // = n*128 + kk
            const int n = idx >> 7, kk = idx & 127;
            WgT[idx] = f2b(W_gcn[kk * HH + n]);
            WpT[idx] = f2b(W_proj[kk * HH + n]);
        }
    }
}

// ===========================================================================
// Persistent kernel, all 64 steps. 512 blocks x 256 thr (2 blocks/CU exact).
// Per step: phase A (partials; mutable data via sc1) -> wave-release barrier
// -> phase B (blocks 0..255 merge+fuse 16 rows each) -> barrier -> next t.
// No __threadfence anywhere: L2 holds only read-only data, never invalidated.
// ===========================================================================
__global__ __launch_bounds__(256, 2) void persist_kernel(
    short* __restrict__ hp0, short* __restrict__ hp1,
    short* __restrict__ hin0, short* __restrict__ hin1,
    short* __restrict__ hinT0, short* __restrict__ hinT1,
    const short* __restrict__ WgT, const short* __restrict__ WpT,
    const float* __restrict__ b_gcn, const float* __restrict__ b_proj,
    const float* __restrict__ W_out, const float* __restrict__ b_out,
    const float* __restrict__ x_seq, const float* __restrict__ m_seq,
    const float* __restrict__ W_in,  const float* __restrict__ b_in,
    float* __restrict__ Opart, float* __restrict__ lpart,
    int* __restrict__ bar1, int* __restrict__ bar2,
    float* __restrict__ out)
{
    __shared__ __align__(16) char pool[47104];
    short* KtP = (short*)pool;              // [2][32*136]  (17408 B)
    short* VtP = (short*)(pool + 17408);    // [2][128*40]  (20480 B)
    short* PtP = (short*)(pool + 37888);    // [4][32*36]   (9216 B)

    const int tid  = threadIdx.x;
    const int wave = tid >> 6, lane = tid & 63;
    const int ln = lane & 15, g = lane >> 4;
    const int qg = blockIdx.x >> 4, split = blockIdx.x & 15;
    const int q0 = qg * 128 + wave * 32;
    const int kbase = split * KPB;

    const int krow = tid >> 3, kcol = (tid & 7) * 16;   // 32 rows x 128 shorts
    const int vrow = tid >> 1, vcol = (tid & 1) * 16;   // 128 rows x 32 shorts

    auto gbar = [&](int* ctr) {
        if (lane == 0)
            __hip_atomic_fetch_add(ctr, 1, __ATOMIC_RELEASE, AGENT);  // drains own vmcnt
        if (tid == 0) {
            int it = 0;
            while (__hip_atomic_load(ctr, __ATOMIC_RELAXED, AGENT) < NSIG && it < SPIN_CAP) {
                ++it; __builtin_amdgcn_s_sleep(1);
            }
        }
        __syncthreads();
    };

    for (int t = 0; t < TT; ++t) {
        const short* hpR   = (t & 1) ? hp1   : hp0;
        short*       hpW   = (t & 1) ? hp0   : hp1;
        const short* hinR  = (t & 1) ? hin1  : hin0;
        short*       hinW  = (t & 1) ? hin0  : hin1;
        const short* hinTR = (t & 1) ? hinT1 : hinT0;
        short*       hinTW = (t & 1) ? hinT0 : hinT1;

        // ================= phase A: attention partials =================
        short8 qf[2][4];
        #pragma unroll
        for (int mt = 0; mt < 2; ++mt)
            #pragma unroll
            for (int kc = 0; kc < 4; ++kc)
                qf[mt][kc] = ldg_sc(&hpR[(q0 + mt * 16 + ln) * HH + kc * 32 + g * 8]);

        f32x4 oacc[2][8] = {};
        float lsum[2][4] = {};
        short8 ksA, ksB, vsA, vsB;

        auto load_tile = [&](int kt_) {
            const int kb = kbase + kt_ * KT;
            ksA = ldg_sc(&hpR  [(kb + krow) * HH + kcol]);
            ksB = ldg_sc(&hpR  [(kb + krow) * HH + kcol + 8]);
            vsA = ldg_sc(&hinTR[(size_t)vrow * NN + kb + vcol]);
            vsB = ldg_sc(&hinTR[(size_t)vrow * NN + kb + vcol + 8]);
        };
        auto store_tile = [&](int b) {
            *(short8*)&KtP[b * 4352 + krow * 136 + kcol]     = ksA;
            *(short8*)&KtP[b * 4352 + krow * 136 + kcol + 8] = ksB;
            *(short8*)&VtP[b * 5120 + vrow * 40 + vcol]      = vsA;
            *(short8*)&VtP[b * 5120 + vrow * 40 + vcol + 8]  = vsB;
        };

        load_tile(0);
        store_tile(0);

        for (int kt = 0; kt < NTILES; ++kt) {
            const int b = kt & 1;
            __syncthreads();

            short8 kf[2][4], vf[8];
            #pragma unroll
            for (int nt = 0; nt < 2; ++nt)
                #pragma unroll
                for (int kc = 0; kc < 4; ++kc)
                    kf[nt][kc] = *(const short8*)&KtP[b * 4352 + (nt * 16 + ln) * 136 + kc * 32 + g * 8];
            #pragma unroll
            for (int dt = 0; dt < 8; ++dt)
                vf[dt] = *(const short8*)&VtP[b * 5120 + (dt * 16 + ln) * 40 + g * 8];

            if (kt + 1 < NTILES) load_tile(kt + 1);

            f32x4 sacc[2][2] = {};
            #pragma unroll
            for (int mt = 0; mt < 2; ++mt)
                #pragma unroll
                for (int nt = 0; nt < 2; ++nt)
                    #pragma unroll
                    for (int kc = 0; kc < 4; ++kc)
                        sacc[mt][nt] = MFMA(qf[mt][kc], kf[nt][kc], sacc[mt][nt]);

            // fixed-shift softmax numerators -> Pt (stride 36: 2 lanes/bank)
            #pragma unroll
            for (int mt = 0; mt < 2; ++mt)
                #pragma unroll
                for (int nt = 0; nt < 2; ++nt)
                    #pragma unroll
                    for (int r = 0; r < 4; ++r) {
                        const float p = __expf(sacc[mt][nt][r] * SCALE - CSHIFT);
                        const short pb = f2b(p);
                        lsum[mt][r] += b2f(pb);
                        PtP[wave * 1152 + (mt * 16 + g * 4 + r) * 36 + nt * 16 + ln] = pb;
                    }

            if (kt + 1 < NTILES) store_tile(b ^ 1);

            __syncthreads();   // Pt RAW fence (round-2 lesson: mandatory)

            short8 pf0, pf1;
            {   // 8B-aligned LDS reads (stride 36)
                union { u64 u[2]; short8 v; } r0, r1;
                r0.u[0] = *(const u64*)&PtP[wave * 1152 + ln * 36 + g * 8];
                r0.u[1] = *(const u64*)&PtP[wave * 1152 + ln * 36 + g * 8 + 4];
                r1.u[0] = *(const u64*)&PtP[wave * 1152 + (16 + ln) * 36 + g * 8];
                r1.u[1] = *(const u64*)&PtP[wave * 1152 + (16 + ln) * 36 + g * 8 + 4];
                pf0 = r0.v; pf1 = r1.v;
            }

            #pragma unroll
            for (int dt = 0; dt < 8; ++dt) {
                oacc[0][dt] = MFMA(pf0, vf[dt], oacc[0][dt]);
                oacc[1][dt] = MFMA(pf1, vf[dt], oacc[1][dt]);
            }
        }

        // l reduction over 16-lane key dim; sc1 partial writes
        #pragma unroll
        for (int mt = 0; mt < 2; ++mt)
            #pragma unroll
            for (int r = 0; r < 4; ++r) {
                float l = lsum[mt][r];
                l += __shfl_xor(l, 1); l += __shfl_xor(l, 2);
                l += __shfl_xor(l, 4); l += __shfl_xor(l, 8);
                if (ln == 0) stg_sc_f(&lpart[split * NN + q0 + mt * 16 + g * 4 + r], l);
            }
        #pragma unroll
        for (int mt = 0; mt < 2; ++mt)
            #pragma unroll
            for (int dt = 0; dt < 8; ++dt)
                #pragma unroll
                for (int r = 0; r < 4; ++r)
                    stg_sc_f(&Opart[((size_t)split * NN + q0 + mt * 16 + g * 4 + r) * HH + dt * 16 + ln],
                             oacc[mt][dt][r]);

        gbar(&bar1[t]);   // all partials at LLC

        // ================= phase B: merge + fuse (blocks 0..255) ==========
        if (blockIdx.x < 256) {
            const int qb = blockIdx.x * 16;
            short* msgb  = (short*)pool;                 // 16*136
            short* hnb   = (short*)pool + 2176;          // 16*136
            short* hpb   = (short*)pool + 4352;          // 16*136
            short* hinb  = (short*)pool + 6528;          // 16*136
            short* hintb = (short*)pool + 8704;          // 128*16
            float* larr  = (float*)((short*)pool + 10752);   // 16
            float* ppd   = larr + 16;                        // 4*16

            // stage h_in(t) rows (sc1) into LDS
            {
                const int q = tid >> 4, off = (tid & 15) * 8;
                *(short8*)&hinb[q * 136 + off] = ldg_sc(&hinR[(qb + q) * HH + off]);
            }
            if (tid < 16) {
                float l = 0.f;
                #pragma unroll
                for (int sp = 0; sp < SPLITS; ++sp)
                    l += __hip_atomic_load(&lpart[sp * NN + qb + tid], __ATOMIC_RELAXED, AGENT);
                larr[tid] = 1.0f / l;
            }
            __syncthreads();

            // merge 16 partials -> msg (bf16 LDS)
            for (int i = tid; i < 16 * 32; i += 256) {
                const int q = i >> 5, d4 = (i & 31) * 4;
                f32x4 s = {};
                #pragma unroll
                for (int sp = 0; sp < SPLITS; ++sp)
                    s += ldg_sc_f4(&Opart[((size_t)sp * NN + qb + q) * HH + d4]);
                const float inv = larr[q];
                short* mp = &msgb[q * 136 + d4];
                mp[0] = f2b(s[0] * inv); mp[1] = f2b(s[1] * inv);
                mp[2] = f2b(s[2] * inv); mp[3] = f2b(s[3] * inv);
            }
            __syncthreads();

            // GEMM1: h_new = relu(msg@Wg + b_gcn + h_in); pred partials
            short8 af[4];
            #pragma unroll
            for (int kc = 0; kc < 4; ++kc)
                af[kc] = *(const short8*)&msgb[ln * 136 + kc * 32 + g * 8];
            float pr[4] = {0.f, 0.f, 0.f, 0.f};
            #pragma unroll
            for (int ni = 0; ni < 2; ++ni) {
                const int nt = wave * 2 + ni;
                f32x4 c = {};
                #pragma unroll
                for (int kc = 0; kc < 4; ++kc)
                    c = MFMA(af[kc], *(const short8*)&WgT[(nt * 16 + ln) * HH + kc * 32 + g * 8], c);
                const float bg = b_gcn[nt * 16 + ln];
                const float wo = W_out[nt * 16 + ln];
                #pragma unroll
                for (int r = 0; r < 4; ++r) {
                    const int q = g * 4 + r;
                    float v = c[r] + bg + b2f(hinb[q * 136 + nt * 16 + ln]);
                    v = v > 0.f ? v : 0.f;
                    hnb[q * 136 + nt * 16 + ln] = f2b(v);
                    pr[r] += v * wo;
                }
            }
            #pragma unroll
            for (int r = 0; r < 4; ++r) {
                float p = pr[r];
                p += __shfl_xor(p, 1); p += __shfl_xor(p, 2);
                p += __shfl_xor(p, 4); p += __shfl_xor(p, 8);
                if (ln == 0) ppd[wave * 16 + g * 4 + r] = p;
            }
            __syncthreads();

            if (tid < 16)
                out[(qb + tid) * TT + t] = ppd[tid] + ppd[16 + tid] + ppd[32 + tid] + ppd[48 + tid] + b_out[0];

            if (t < TT - 1) {
                // GEMM2: h_proj(t+1) = h_new @ W_proj + b_proj -> hpb
                short8 hf[4];
                #pragma unroll
                for (int kc = 0; kc < 4; ++kc)
                    hf[kc] = *(const short8*)&hnb[ln * 136 + kc * 32 + g * 8];
                #pragma unroll
                for (int ni = 0; ni < 2; ++ni) {
                    const int nt = wave * 2 + ni;
                    f32x4 c = {};
                    #pragma unroll
                    for (int kc = 0; kc < 4; ++kc)
                        c = MFMA(hf[kc], *(const short8*)&WpT[(nt * 16 + ln) * HH + kc * 32 + g * 8], c);
                    const float bp = b_proj[nt * 16 + ln];
                    #pragma unroll
                    for (int r = 0; r < 4; ++r)
                        hpb[(g * 4 + r) * 136 + nt * 16 + ln] = f2b(c[r] + bp);
                }

                // h_in(t+1) -> hinb (reuse; GEMM1 reads done) + hintb
                for (int i = tid; i < 16 * HH; i += 256) {
                    const int q = i >> 7, j = i & 127;
                    float hi = x_seq[(qb + q) * TT + t + 1] * W_in[j]
                             + m_seq[(qb + q) * TT + t + 1] * W_in[HH + j] + b_in[j];
                    hi = hi > 0.f ? hi : 0.f;
                    const short hb = f2b(hi);
                    hinb[q * 136 + j] = hb;
                    hintb[j * 16 + q] = hb;
                }
                __syncthreads();

                // cooperative sc1 stores: hp / hin (512 8B-chunks each)
                for (int c = tid; c < 512; c += 256) {
                    const int q = c >> 5, off = (c & 31) * 4;
                    stg_sc8(&hpW [(qb + q) * HH + off], *(const u64*)&hpb [q * 136 + off]);
                    stg_sc8(&hinW[(qb + q) * HH + off], *(const u64*)&hinb[q * 136 + off]);
                }
                // hinT: 128 j-rows x 16 n (4 chunks of 4 shorts each)
                for (int c = tid; c < 512; c += 256) {
                    const int j = c >> 2, off = (c & 3) * 4;
                    stg_sc8(&hinTW[(size_t)j * NN + qb + off], *(const u64*)&hintb[j * 16 + off]);
                }
            }
        }

        if (t < TT - 1) gbar(&bar2[t]);   // phase-B state at LLC before next phase A
    }
}

// ===========================================================================
extern "C" void kernel_launch(void* const* d_in, const int* in_sizes, int n_in,
                              void* d_out, int out_size, void* d_ws, size_t ws_size,
                              hipStream_t stream) {
    const float* x_seq  = (const float*)d_in[0];
    const float* m_seq  = (const float*)d_in[1];
    const float* W_in   = (const float*)d_in[2];
    const float* b_in   = (const float*)d_in[3];
    const float* W_proj = (const float*)d_in[4];
    const float* b_proj = (const float*)d_in[5];
    const float* W_gcn  = (const float*)d_in[6];
    const float* b_gcn  = (const float*)d_in[7];
    const float* W_out  = (const float*)d_in[8];
    const float* b_out  = (const float*)d_in[9];
    float* out = (float*)d_out;

    // ws carve (~40 MB): hp x2 | hin x2 | hinT x2 | WgT | WpT | lpart | ctrl | Opart
    char* base = (char*)d_ws;
    const size_t MB = 1 << 20;
    short* hp0   = (short*)(base + 0 * MB);
    short* hp1   = (short*)(base + 1 * MB);
    short* hin0  = (short*)(base + 2 * MB);
    short* hin1  = (short*)(base + 3 * MB);
    short* hinT0 = (short*)(base + 4 * MB);
    short* hinT1 = (short*)(base + 5 * MB);
    short* WgT   = (short*)(base + 6 * MB);
    short* WpT   = (short*)(base + 6 * MB + 32768);
    float* lpart = (float*)(base + 6 * MB + 65536);            // 256 KB
    int*   ctrl  = (int*)  (base + 6 * MB + 65536 + 262144);   // bar1[64] + bar2[64]
    int*   bar1  = ctrl;
    int*   bar2  = ctrl + 64;
    float* Opart = (float*)(base + 8 * MB);                    // 32 MB

    hipMemsetAsync(ctrl, 0, 128 * sizeof(int), stream);
    prep_kernel<<<272, 256, 0, stream>>>(x_seq, m_seq, W_in, b_in, W_proj, b_proj,
                                         W_gcn, hp0, hin0, hinT0, WgT, WpT);
    persist_kernel<<<NBLK, 256, 0, stream>>>(hp0, hp1, hin0, hin1, hinT0, hinT1,
                                             WgT, WpT, b_gcn, b_proj, W_out, b_out,
                                             x_seq, m_seq, W_in, b_in,
                                             Opart, lpart, bar1, bar2, out);
}

// Round 7
// 7873.228 us; speedup vs baseline: 2.3564x; 2.0662x over previous
//
#include <hip/hip_runtime.h>
#include <math.h>

#define NN 4096
#define TT 64
#define HH 128
#define QB 32               // q rows per block
#define NBLK (NN / QB)      // 128 blocks
#define NWAVE 8
#define KPW (NN / NWAVE)    // 512 keys per wave
#define KT 32
#define TPW (KPW / KT)      // 16 tiles per wave
#define SCALE 0.08838834764831845f   // 1/sqrt(128)
#define CSHIFT 16.0f
#define SPIN_CAP 5000000
#define AGENT __HIP_MEMORY_SCOPE_AGENT

typedef __attribute__((ext_vector_type(8))) short short8;
typedef __attribute__((ext_vector_type(4))) float f32x4;
#define MFMA(a, b, c) __builtin_amdgcn_mfma_f32_16x16x32_bf16((a), (b), (c), 0, 0, 0)

// ---- bf16 helpers (RNE) ----
__device__ __forceinline__ short f2b(float f) {
    union { float f; unsigned u; } v; v.f = f;
    unsigned r = v.u + 0x7fffu + ((v.u >> 16) & 1u);
    return (short)(r >> 16);
}
__device__ __forceinline__ float b2f(short s) {
    union { unsigned u; float f; } v; v.u = ((unsigned)(unsigned short)s) << 16;
    return v.f;
}

// Wave-local LDS fence: HW-completes outstanding LDS ops AND stops the
// compiler's per-thread alias analysis from reordering cross-lane ds
// accesses across it (round-2 lesson, without round-6's block-wide syncs).
__device__ __forceinline__ void lds_fence() {
    __asm__ __volatile__("s_waitcnt lgkmcnt(0)" ::: "memory");
}
__device__ __forceinline__ void vm_drain() {
    __asm__ __volatile__("s_waitcnt vmcnt(0)" ::: "memory");
}

// ===========================================================================
// prep: once per launch. bf16 weight transposes; hp0 = b_proj (h0=0);
// hin0/hinT0 from x[:,0], m[:,0].
// ===========================================================================
__global__ __launch_bounds__(256) void prep_kernel(
    const float* __restrict__ x_seq, const float* __restrict__ m_seq,
    const float* __restrict__ W_in,  const float* __restrict__ b_in,
    const float* __restrict__ W_proj,const float* __restrict__ b_proj,
    const float* __restrict__ W_gcn,
    short* __restrict__ hp0, short* __restrict__ hin0, short* __restrict__ hinT0,
    short* __restrict__ WgT, short* __restrict__ WpT)
{
    const int b = blockIdx.x, tid = threadIdx.x;
    if (b < 256) {
        const int n0 = b * 16;
        for (int i = tid; i < 16 * HH; i += 256) {
            const int q = i >> 7, j = i & 127, n = n0 + q;
            hp0[n * HH + j] = f2b(b_proj[j]);
            float hi = x_seq[n * TT] * W_in[j] + m_seq[n * TT] * W_in[HH + j] + b_in[j];
            hi = hi > 0.f ? hi : 0.f;
            const short hb = f2b(hi);
            hin0[n * HH + j] = hb;
            hinT0[j * NN + n] = hb;
        }
    } else {
        const int wb = b - 256;
        #pragma unroll
        for (int k = 0; k < 4; ++k) {
            const int idx = wb * 1024 + k * 256 + tid;   // = n*128 + kk
            const int n = idx >> 7, kk = idx & 127;
            WgT[idx] = f2b(W_gcn[kk * HH + n]);
            WpT[idx] = f2b(W_proj[kk * HH + n]);
        }
    }
}

// ===========================================================================
// Persistent kernel: 128 blocks x 512 thr (8 waves), all 64 steps.
// Block owns q rows [32b, 32b+32): COMPLETE rows (no cross-block partials).
// Wave w covers keys [512w, 512w+512); K/V fragments read directly from L2
// (global); O partials merged across waves via LDS ds_add_f32.
// Cross-block state per step: hp/hinT ping-pong, normal cached accesses +
// ONE __threadfence (wbL2+inv) per block per step before the barrier signal.
// ===========================================================================
__global__ __launch_bounds__(512, 2) void persist_kernel(
    short* __restrict__ hp0, short* __restrict__ hp1,
    short* __restrict__ hinT0, short* __restrict__ hinT1,
    const short* __restrict__ hin0,
    const short* __restrict__ WgT, const short* __restrict__ WpT,
    const float* __restrict__ b_gcn, const float* __restrict__ b_proj,
    const float* __restrict__ W_out, const float* __restrict__ b_out,
    const float* __restrict__ x_seq, const float* __restrict__ m_seq,
    const float* __restrict__ W_in,  const float* __restrict__ b_in,
    int* __restrict__ barL, int* __restrict__ barR,
    float* __restrict__ out)
{
    __shared__ __align__(16) char pool[54912];
    float* OaccF = (float*)pool;                      // [32][132]  16896 B
    float* lacc  = (float*)(pool + 16896);            // [32]         128 B
    short* hinL  = (short*)(pool + 17024);            // [32*136]    8704 B
    short* hnb   = (short*)(pool + 25728);            // [32*136]    8704 B
    short* PtP   = (short*)(pool + 34432);            // [8][32*40] 20480 B

    const int tid  = threadIdx.x;
    const int wave = tid >> 6, lane = tid & 63;
    const int ln = lane & 15, g = lane >> 4;
    const int qb = blockIdx.x * QB;

    for (int t = 0; t < TT; ++t) {
        const short* hpR = (t & 1) ? hp1   : hp0;
        short*       hpW = (t & 1) ? hp0   : hp1;
        const short* hTR = (t & 1) ? hinT1 : hinT0;
        short*       hTW = (t & 1) ? hinT0 : hinT1;

        // ---- per-step LDS init (h_in staging at t=0; zero O/l accumulators)
        if (t == 0) {
            const int q = tid >> 4, c = (tid & 15) * 8;
            *(short8*)&hinL[q * 136 + c] = *(const short8*)&hin0[(qb + q) * HH + c];
        }
        for (int i = tid; i < 32 * 132; i += 512) OaccF[i] = 0.f;
        if (tid < 32) lacc[tid] = 0.f;
        __syncthreads();

        // ================= phase A: this wave's 512 keys =================
        short8 qf[2][4];
        #pragma unroll
        for (int mt = 0; mt < 2; ++mt)
            #pragma unroll
            for (int kc = 0; kc < 4; ++kc)
                qf[mt][kc] = *(const short8*)&hpR[(qb + mt * 16 + ln) * HH + kc * 32 + g * 8];

        f32x4 oacc[2][8] = {};
        float lsum[2][4] = {};
        short* Pt = &PtP[wave * 1280];   // 32 x 40 shorts

        for (int kt = 0; kt < TPW; ++kt) {
            const int kb = wave * KPW + kt * KT;

            // K/V fragments direct from global (L2-hot)
            short8 kf[2][4], vf[8];
            #pragma unroll
            for (int nt = 0; nt < 2; ++nt)
                #pragma unroll
                for (int kc = 0; kc < 4; ++kc)
                    kf[nt][kc] = *(const short8*)&hpR[(kb + nt * 16 + ln) * HH + kc * 32 + g * 8];
            #pragma unroll
            for (int dt = 0; dt < 8; ++dt)
                vf[dt] = *(const short8*)&hTR[(size_t)(dt * 16 + ln) * NN + kb + g * 8];

            // scores S[32x32]
            f32x4 sacc[2][2] = {};
            #pragma unroll
            for (int mt = 0; mt < 2; ++mt)
                #pragma unroll
                for (int nt = 0; nt < 2; ++nt)
                    #pragma unroll
                    for (int kc = 0; kc < 4; ++kc)
                        sacc[mt][nt] = MFMA(qf[mt][kc], kf[nt][kc], sacc[mt][nt]);

            lds_fence();   // WAR: prior tile's Pt reads complete before overwrite

            // fixed-shift softmax numerators -> Pt (stride 40: b128-readable)
            #pragma unroll
            for (int mt = 0; mt < 2; ++mt)
                #pragma unroll
                for (int nt = 0; nt < 2; ++nt)
                    #pragma unroll
                    for (int r = 0; r < 4; ++r) {
                        const float p = __expf(sacc[mt][nt][r] * SCALE - CSHIFT);
                        const short pb = f2b(p);
                        lsum[mt][r] += b2f(pb);
                        Pt[(mt * 16 + g * 4 + r) * 40 + nt * 16 + ln] = pb;
                    }

            lds_fence();   // RAW: cross-lane Pt writes complete before A-frag reads

            short8 pf0 = *(const short8*)&Pt[ln * 40 + g * 8];
            short8 pf1 = *(const short8*)&Pt[(16 + ln) * 40 + g * 8];

            #pragma unroll
            for (int dt = 0; dt < 8; ++dt) {
                oacc[0][dt] = MFMA(pf0, vf[dt], oacc[0][dt]);
                oacc[1][dt] = MFMA(pf1, vf[dt], oacc[1][dt]);
            }
        }

        // ---- in-block merge: l and O into LDS accumulators
        #pragma unroll
        for (int mt = 0; mt < 2; ++mt)
            #pragma unroll
            for (int r = 0; r < 4; ++r) {
                float l = lsum[mt][r];
                l += __shfl_xor(l, 1); l += __shfl_xor(l, 2);
                l += __shfl_xor(l, 4); l += __shfl_xor(l, 8);
                if (ln == 0) atomicAdd(&lacc[mt * 16 + g * 4 + r], l);
            }
        #pragma unroll
        for (int mt = 0; mt < 2; ++mt)
            #pragma unroll
            for (int dt = 0; dt < 8; ++dt)
                #pragma unroll
                for (int r = 0; r < 4; ++r)
                    atomicAdd(&OaccF[(mt * 16 + g * 4 + r) * 132 + dt * 16 + ln],
                              oacc[mt][dt][r]);
        __syncthreads();   // merge complete

        // ================= fuse (waves 0,1: m-tile = wave) =================
        if (wave < 2) {
            const float invq = 1.0f / lacc[wave * 16 + ln];
            short8 af[4];
            #pragma unroll
            for (int kc = 0; kc < 4; ++kc) {
                const float* op = &OaccF[(wave * 16 + ln) * 132 + kc * 32 + g * 8];
                const f32x4 o0 = *(const f32x4*)op;
                const f32x4 o1 = *(const f32x4*)(op + 4);
                short8 a;
                a[0] = f2b(o0[0] * invq); a[1] = f2b(o0[1] * invq);
                a[2] = f2b(o0[2] * invq); a[3] = f2b(o0[3] * invq);
                a[4] = f2b(o1[0] * invq); a[5] = f2b(o1[1] * invq);
                a[6] = f2b(o1[2] * invq); a[7] = f2b(o1[3] * invq);
                af[kc] = a;
            }
            // GEMM1: h_new = relu(msg @ W_gcn + b_gcn + h_in); pred partials
            float pr[4] = {0.f, 0.f, 0.f, 0.f};
            #pragma unroll
            for (int nt = 0; nt < 8; ++nt) {
                f32x4 c = {};
                #pragma unroll
                for (int kc = 0; kc < 4; ++kc)
                    c = MFMA(af[kc], *(const short8*)&WgT[(nt * 16 + ln) * HH + kc * 32 + g * 8], c);
                const float bg = b_gcn[nt * 16 + ln];
                const float wo = W_out[nt * 16 + ln];
                #pragma unroll
                for (int r = 0; r < 4; ++r) {
                    const int q = wave * 16 + g * 4 + r;
                    float v = c[r] + bg + b2f(hinL[q * 136 + nt * 16 + ln]);
                    v = v > 0.f ? v : 0.f;
                    hnb[q * 136 + nt * 16 + ln] = f2b(v);
                    pr[r] += v * wo;
                }
            }
            #pragma unroll
            for (int r = 0; r < 4; ++r) {
                float p = pr[r];
                p += __shfl_xor(p, 1); p += __shfl_xor(p, 2);
                p += __shfl_xor(p, 4); p += __shfl_xor(p, 8);
                if (ln == 0) out[(qb + wave * 16 + g * 4 + r) * TT + t] = p + b_out[0];
            }
        }
        __syncthreads();   // hnb ready; hinL reads done (safe to overwrite)

        if (t < TT - 1) {
            if (wave < 2) {
                // GEMM2: h_proj(t+1) = h_new @ W_proj + b_proj -> hpW (global)
                short8 hf[4];
                #pragma unroll
                for (int kc = 0; kc < 4; ++kc)
                    hf[kc] = *(const short8*)&hnb[(wave * 16 + ln) * 136 + kc * 32 + g * 8];
                #pragma unroll
                for (int nt = 0; nt < 8; ++nt) {
                    f32x4 c = {};
                    #pragma unroll
                    for (int kc = 0; kc < 4; ++kc)
                        c = MFMA(hf[kc], *(const short8*)&WpT[(nt * 16 + ln) * HH + kc * 32 + g * 8], c);
                    const float bp = b_proj[nt * 16 + ln];
                    #pragma unroll
                    for (int r = 0; r < 4; ++r)
                        hpW[(qb + wave * 16 + g * 4 + r) * HH + nt * 16 + ln] = f2b(c[r] + bp);
                }
            } else if (wave < 4) {
                // h_in(t+1): refresh hinL (LDS, block-local) + hinT (global)
                for (int i = (wave - 2) * 64 + lane; i < 32 * HH; i += 128) {
                    const int q = i >> 7, j = i & 127;
                    float hi = x_seq[(qb + q) * TT + t + 1] * W_in[j]
                             + m_seq[(qb + q) * TT + t + 1] * W_in[HH + j] + b_in[j];
                    hi = hi > 0.f ? hi : 0.f;
                    const short hb = f2b(hi);
                    hinL[q * 136 + j] = hb;
                    hTW[(size_t)j * NN + qb + q] = hb;
                }
            }

            // ======= step boundary: release + grid barrier + acquire =======
            vm_drain();        // each wave drains its own global stores to L2
            __syncthreads();
            if (tid == 0) {
                __threadfence();   // wbL2 (publish block's state) + inv (drop stale)
                const int line = blockIdx.x & 7;
                int old = __hip_atomic_fetch_add(&barL[t * 8 + line], 1,
                                                 __ATOMIC_RELEASE, AGENT);
                if (old == (NBLK / 8) - 1)
                    __hip_atomic_fetch_add(&barR[t], 1, __ATOMIC_RELEASE, AGENT);
                int it = 0;
                while (__hip_atomic_load(&barR[t], __ATOMIC_RELAXED, AGENT) < 8
                       && it < SPIN_CAP) { ++it; __builtin_amdgcn_s_sleep(2); }
            }
            __syncthreads();   // no wave reads global state until barrier passed
        }
    }
}

// ===========================================================================
extern "C" void kernel_launch(void* const* d_in, const int* in_sizes, int n_in,
                              void* d_out, int out_size, void* d_ws, size_t ws_size,
                              hipStream_t stream) {
    const float* x_seq  = (const float*)d_in[0];
    const float* m_seq  = (const float*)d_in[1];
    const float* W_in   = (const float*)d_in[2];
    const float* b_in   = (const float*)d_in[3];
    const float* W_proj = (const float*)d_in[4];
    const float* b_proj = (const float*)d_in[5];
    const float* W_gcn  = (const float*)d_in[6];
    const float* b_gcn  = (const float*)d_in[7];
    const float* W_out  = (const float*)d_in[8];
    const float* b_out  = (const float*)d_in[9];
    float* out = (float*)d_out;

    // ws carve (~6 MB): hp x2 | hinT x2 | hin0 | WgT | WpT | barriers
    char* base = (char*)d_ws;
    const size_t MB = 1 << 20;
    short* hp0   = (short*)(base + 0 * MB);
    short* hp1   = (short*)(base + 1 * MB);
    short* hinT0 = (short*)(base + 2 * MB);
    short* hinT1 = (short*)(base + 3 * MB);
    short* hin0  = (short*)(base + 4 * MB);
    short* WgT   = (short*)(base + 5 * MB);
    short* WpT   = (short*)(base + 5 * MB + 32768);
    int*   barL  = (int*)  (base + 5 * MB + 65536);   // [TT*8]
    int*   barR  = barL + TT * 8;                     // [TT]

    hipMemsetAsync(barL, 0, (TT * 8 + TT) * sizeof(int), stream);
    prep_kernel<<<272, 256, 0, stream>>>(x_seq, m_seq, W_in, b_in, W_proj, b_proj,
                                         W_gcn, hp0, hin0, hinT0, WgT, WpT);
    persist_kernel<<<NBLK, 512, 0, stream>>>(hp0, hp1, hinT0, hinT1, hin0,
                                             WgT, WpT, b_gcn, b_proj, W_out, b_out,
                                             x_seq, m_seq, W_in, b_in,
                                             barL, barR, out);
}

// Round 8
// 5113.836 us; speedup vs baseline: 3.6279x; 1.5396x over previous
//
#include <hip/hip_runtime.h>
#include <math.h>

#define NN 4096
#define TT 64
#define HH 128
#define QB 16               // q rows per block
#define NWAVE 8
#define KPW (NN / NWAVE)    // 512 keys per wave
#define KT 32
#define TPW (KPW / KT)      // 16 tiles per wave
#define SCALE 0.08838834764831845f   // 1/sqrt(128)
#define CSHIFT 16.0f

typedef __attribute__((ext_vector_type(8))) short short8;
typedef __attribute__((ext_vector_type(4))) float f32x4;
typedef unsigned long long u64;
#define MFMA(a, b, c) __builtin_amdgcn_mfma_f32_16x16x32_bf16((a), (b), (c), 0, 0, 0)

// ---- bf16 helpers (RNE) ----
__device__ __forceinline__ short f2b(float f) {
    union { float f; unsigned u; } v; v.f = f;
    unsigned r = v.u + 0x7fffu + ((v.u >> 16) & 1u);
    return (short)(r >> 16);
}
__device__ __forceinline__ float b2f(short s) {
    union { unsigned u; float f; } v; v.u = ((unsigned)(unsigned short)s) << 16;
    return v.f;
}

// Wave-local LDS fence (R7-proven): completes outstanding ds ops and blocks
// compiler reordering of cross-lane LDS accesses (round-2 lesson), without
// a block-wide barrier.
__device__ __forceinline__ void lds_fence() {
    __asm__ __volatile__("s_waitcnt lgkmcnt(0)" ::: "memory");
}

// ===========================================================================
// prep: once per launch. bf16 weight transposes; hp0 = b_proj (h0=0);
// hinT0 from x[:,0], m[:,0].
// ===========================================================================
__global__ __launch_bounds__(256) void prep_kernel(
    const float* __restrict__ x_seq, const float* __restrict__ m_seq,
    const float* __restrict__ W_in,  const float* __restrict__ b_in,
    const float* __restrict__ W_proj,const float* __restrict__ b_proj,
    const float* __restrict__ W_gcn,
    short* __restrict__ hp0, short* __restrict__ hinT0,
    short* __restrict__ WgT, short* __restrict__ WpT)
{
    const int b = blockIdx.x, tid = threadIdx.x;
    if (b < 256) {
        const int n0 = b * 16;
        for (int i = tid; i < 16 * HH; i += 256) {
            const int q = i >> 7, j = i & 127, n = n0 + q;
            hp0[n * HH + j] = f2b(b_proj[j]);
            float hi = x_seq[n * TT] * W_in[j] + m_seq[n * TT] * W_in[HH + j] + b_in[j];
            hi = hi > 0.f ? hi : 0.f;
            hinT0[j * NN + n] = f2b(hi);
        }
    } else {
        const int wb = b - 256;
        #pragma unroll
        for (int k = 0; k < 4; ++k) {
            const int idx = wb * 1024 + k * 256 + tid;   // = n*128 + kk
            const int n = idx >> 7, kk = idx & 127;
            WgT[idx] = f2b(W_gcn[kk * HH + n]);
            WpT[idx] = f2b(W_proj[kk * HH + n]);
        }
    }
}

// ===========================================================================
// step_kernel: ONE launch per timestep (kernel boundary = the only grid-wide
// sync; HW coherence — no fences/sc1/barriers, L2 never invalidated).
// 256 blocks x 512 thr (8 waves, 2 waves/SIMD). Block owns q rows
// [16b, 16b+16) COMPLETELY: wave w covers keys [512w, 512w+512) reading K/V
// fragments straight from global (L2-hot); O/l merged in-block via LDS
// atomics; epilogue (GEMM1 + pred + GEMM2 + h_in(t+1)) distributed over all
// 8 waves (column tile nt = wave). State ping-pongs across launches.
// ===========================================================================
__global__ __launch_bounds__(512, 2) void step_kernel(
    const short* __restrict__ hpR, short* __restrict__ hpW,
    const short* __restrict__ hTR, short* __restrict__ hTW,
    const short* __restrict__ WgT, const short* __restrict__ WpT,
    const float* __restrict__ b_gcn, const float* __restrict__ b_proj,
    const float* __restrict__ W_out, const float* __restrict__ b_out,
    const float* __restrict__ x_seq, const float* __restrict__ m_seq,
    const float* __restrict__ W_in,  const float* __restrict__ b_in,
    float* __restrict__ out, int t)
{
    __shared__ __align__(16) char pool[32768];
    float* OaccF = (float*)pool;                 // [16][132]  8448 B
    float* lacc  = (float*)(pool + 8448);        // [16]         64 B
    short* msgb  = (short*)(pool + 8512);        // 16*136     4352 B
    short* hnb   = (short*)(pool + 12864);       // 16*136     4352 B
    float* ppd   = (float*)(pool + 17216);       // [8][16]     512 B
    short* hintb = (short*)(pool + 17728);       // 128*16     4096 B
    short* PtP   = (short*)(pool + 21824);       // [8][16*40] 10240 B

    const int tid  = threadIdx.x;
    const int wave = tid >> 6, lane = tid & 63;
    const int ln = lane & 15, g = lane >> 4;
    const int qb = blockIdx.x * QB;

    // zero O/l accumulators
    for (int i = tid; i < 16 * 132; i += 512) OaccF[i] = 0.f;
    if (tid < 16) lacc[tid] = 0.f;
    __syncthreads();

    // ================= phase A: this wave's 512 keys =================
    short8 qf[4];
    #pragma unroll
    for (int kc = 0; kc < 4; ++kc)
        qf[kc] = *(const short8*)&hpR[(qb + ln) * HH + kc * 32 + g * 8];

    f32x4 oacc[8] = {};
    float lsum[4] = {0.f, 0.f, 0.f, 0.f};
    short* Pt = &PtP[wave * 640];   // 16 x 40 shorts

    short8 kf[2][4], vf[8], kf2[2][4], vf2[8];
    {
        const int kb = wave * KPW;
        #pragma unroll
        for (int nt = 0; nt < 2; ++nt)
            #pragma unroll
            for (int kc = 0; kc < 4; ++kc)
                kf[nt][kc] = *(const short8*)&hpR[(kb + nt * 16 + ln) * HH + kc * 32 + g * 8];
        #pragma unroll
        for (int dt = 0; dt < 8; ++dt)
            vf[dt] = *(const short8*)&hTR[(size_t)(dt * 16 + ln) * NN + kb + g * 8];
    }

    for (int kt = 0; kt < TPW; ++kt) {
        // prefetch next tile (register double buffer)
        if (kt + 1 < TPW) {
            const int kb = wave * KPW + (kt + 1) * KT;
            #pragma unroll
            for (int nt = 0; nt < 2; ++nt)
                #pragma unroll
                for (int kc = 0; kc < 4; ++kc)
                    kf2[nt][kc] = *(const short8*)&hpR[(kb + nt * 16 + ln) * HH + kc * 32 + g * 8];
            #pragma unroll
            for (int dt = 0; dt < 8; ++dt)
                vf2[dt] = *(const short8*)&hTR[(size_t)(dt * 16 + ln) * NN + kb + g * 8];
        }

        // scores S[16 x 32]
        f32x4 sacc[2] = {};
        #pragma unroll
        for (int nt = 0; nt < 2; ++nt)
            #pragma unroll
            for (int kc = 0; kc < 4; ++kc)
                sacc[nt] = MFMA(qf[kc], kf[nt][kc], sacc[nt]);

        lds_fence();   // WAR: prior tile's Pt reads complete before overwrite

        // fixed-shift softmax numerators -> Pt; l accumulates rounded p
        #pragma unroll
        for (int nt = 0; nt < 2; ++nt)
            #pragma unroll
            for (int r = 0; r < 4; ++r) {
                const float p = __expf(sacc[nt][r] * SCALE - CSHIFT);
                const short pb = f2b(p);
                lsum[r] += b2f(pb);
                Pt[(g * 4 + r) * 40 + nt * 16 + ln] = pb;
            }

        lds_fence();   // RAW: cross-lane Pt writes complete before A-frag reads

        short8 pf = *(const short8*)&Pt[ln * 40 + g * 8];

        #pragma unroll
        for (int dt = 0; dt < 8; ++dt)
            oacc[dt] = MFMA(pf, vf[dt], oacc[dt]);

        if (kt + 1 < TPW) {
            #pragma unroll
            for (int nt = 0; nt < 2; ++nt)
                #pragma unroll
                for (int kc = 0; kc < 4; ++kc)
                    kf[nt][kc] = kf2[nt][kc];
            #pragma unroll
            for (int dt = 0; dt < 8; ++dt)
                vf[dt] = vf2[dt];
        }
    }

    // ---- in-block merge across the 8 waves (LDS atomics)
    #pragma unroll
    for (int r = 0; r < 4; ++r) {
        float l = lsum[r];
        l += __shfl_xor(l, 1); l += __shfl_xor(l, 2);
        l += __shfl_xor(l, 4); l += __shfl_xor(l, 8);
        if (ln == 0) atomicAdd(&lacc[g * 4 + r], l);
    }
    #pragma unroll
    for (int dt = 0; dt < 8; ++dt)
        #pragma unroll
        for (int r = 0; r < 4; ++r)
            atomicAdd(&OaccF[(g * 4 + r) * 132 + dt * 16 + ln], oacc[dt][r]);
    __syncthreads();

    // ================= epilogue (all 8 waves; column tile nt = wave) =======
    // msg = O/l -> bf16 LDS (A-frag-readable)
    {
        const int q = tid >> 5, d4 = (tid & 31) * 4;
        const float inv = 1.0f / lacc[q];
        const f32x4 s = *(const f32x4*)&OaccF[q * 132 + d4];
        short* mp = &msgb[q * 136 + d4];
        mp[0] = f2b(s[0] * inv); mp[1] = f2b(s[1] * inv);
        mp[2] = f2b(s[2] * inv); mp[3] = f2b(s[3] * inv);
    }
    __syncthreads();

    // GEMM1: h_new = relu(msg @ W_gcn + b_gcn + h_in); pred partials
    const int nt = wave;
    short8 af[4];
    #pragma unroll
    for (int kc = 0; kc < 4; ++kc)
        af[kc] = *(const short8*)&msgb[ln * 136 + kc * 32 + g * 8];
    {
        f32x4 c = {};
        #pragma unroll
        for (int kc = 0; kc < 4; ++kc)
            c = MFMA(af[kc], *(const short8*)&WgT[(nt * 16 + ln) * HH + kc * 32 + g * 8], c);
        const int j = nt * 16 + ln;
        const float bg = b_gcn[j];
        const float wo = W_out[j];
        const float wj0 = W_in[j], wj1 = W_in[HH + j], bj = b_in[j];
        float pr[4];
        #pragma unroll
        for (int r = 0; r < 4; ++r) {
            const int q = g * 4 + r;
            // recompute h_in(t) for the residual (bf16-rounded for parity)
            float hi = x_seq[(qb + q) * TT + t] * wj0 + m_seq[(qb + q) * TT + t] * wj1 + bj;
            hi = hi > 0.f ? hi : 0.f;
            float v = c[r] + bg + b2f(f2b(hi));
            v = v > 0.f ? v : 0.f;
            hnb[q * 136 + j] = f2b(v);
            pr[r] = v * wo;
        }
        #pragma unroll
        for (int r = 0; r < 4; ++r) {
            float p = pr[r];
            p += __shfl_xor(p, 1); p += __shfl_xor(p, 2);
            p += __shfl_xor(p, 4); p += __shfl_xor(p, 8);
            if (ln == 0) ppd[wave * 16 + g * 4 + r] = p;
        }
    }
    __syncthreads();

    if (tid < 16) {
        float p = b_out[0];
        #pragma unroll
        for (int w = 0; w < 8; ++w) p += ppd[w * 16 + tid];
        out[(qb + tid) * TT + t] = p;
    }

    if (t < TT - 1) {
        // GEMM2: h_proj(t+1) = h_new @ W_proj + b_proj -> hpW
        short8 hf[4];
        #pragma unroll
        for (int kc = 0; kc < 4; ++kc)
            hf[kc] = *(const short8*)&hnb[ln * 136 + kc * 32 + g * 8];
        {
            f32x4 c = {};
            #pragma unroll
            for (int kc = 0; kc < 4; ++kc)
                c = MFMA(hf[kc], *(const short8*)&WpT[(nt * 16 + ln) * HH + kc * 32 + g * 8], c);
            const float bp = b_proj[nt * 16 + ln];
            #pragma unroll
            for (int r = 0; r < 4; ++r)
                hpW[(qb + g * 4 + r) * HH + nt * 16 + ln] = f2b(c[r] + bp);
        }

        // h_in(t+1) -> hinT(t+1) (LDS transpose then 8B chunk stores)
        {
            const int q = tid >> 7, base = (tid & 127);   // 4 (q) x 128 (j) per pass
            #pragma unroll
            for (int qq = 0; qq < 4; ++qq) {
                const int qi = qq * 4 + q, j = base;
                float hi = x_seq[(qb + qi) * TT + t + 1] * W_in[j]
                         + m_seq[(qb + qi) * TT + t + 1] * W_in[HH + j] + b_in[j];
                hi = hi > 0.f ? hi : 0.f;
                hintb[j * 16 + qi] = f2b(hi);
            }
        }
        __syncthreads();
        {
            const int j = tid >> 2, off = (tid & 3) * 4;
            *(u64*)&hTW[(size_t)j * NN + qb + off] = *(const u64*)&hintb[j * 16 + off];
        }
    }
}

// ===========================================================================
extern "C" void kernel_launch(void* const* d_in, const int* in_sizes, int n_in,
                              void* d_out, int out_size, void* d_ws, size_t ws_size,
                              hipStream_t stream) {
    const float* x_seq  = (const float*)d_in[0];
    const float* m_seq  = (const float*)d_in[1];
    const float* W_in   = (const float*)d_in[2];
    const float* b_in   = (const float*)d_in[3];
    const float* W_proj = (const float*)d_in[4];
    const float* b_proj = (const float*)d_in[5];
    const float* W_gcn  = (const float*)d_in[6];
    const float* b_gcn  = (const float*)d_in[7];
    const float* W_out  = (const float*)d_in[8];
    const float* b_out  = (const float*)d_in[9];
    float* out = (float*)d_out;

    // ws carve (~5 MB): hp x2 | hinT x2 | WgT | WpT
    char* base = (char*)d_ws;
    const size_t MB = 1 << 20;
    short* hp0   = (short*)(base + 0 * MB);
    short* hp1   = (short*)(base + 1 * MB);
    short* hinT0 = (short*)(base + 2 * MB);
    short* hinT1 = (short*)(base + 3 * MB);
    short* WgT   = (short*)(base + 4 * MB);
    short* WpT   = (short*)(base + 4 * MB + 32768);

    prep_kernel<<<272, 256, 0, stream>>>(x_seq, m_seq, W_in, b_in, W_proj, b_proj,
                                         W_gcn, hp0, hinT0, WgT, WpT);

    for (int t = 0; t < TT; ++t) {
        const short* hpR = (t & 1) ? hp1   : hp0;
        short*       hpW = (t & 1) ? hp0   : hp1;
        const short* hTR = (t & 1) ? hinT1 : hinT0;
        short*       hTW = (t & 1) ? hinT0 : hinT1;
        step_kernel<<<NN / QB, 512, 0, stream>>>(hpR, hpW, hTR, hTW,
                                                 WgT, WpT, b_gcn, b_proj, W_out, b_out,
                                                 x_seq, m_seq, W_in, b_in, out, t);
    }
}

// Round 9
// 2626.457 us; speedup vs baseline: 7.0637x; 1.9470x over previous
//
#include <hip/hip_runtime.h>
#include <math.h>

#define NN 4096
#define TT 64
#define HH 128
#define NNP 4160            // hinT row stride in shorts: 8320B = 65*128B (kills 8KB L2 set-aliasing)
#define SPLITS 8
#define KPB (NN / SPLITS)   // 512 keys per phase-A block
#define KT 32
#define NTILES (KPB / KT)   // 16
#define SCALE 0.08838834764831845f   // 1/sqrt(128)
#define CSHIFT 16.0f

typedef __attribute__((ext_vector_type(8))) short short8;
typedef __attribute__((ext_vector_type(4))) float f32x4;
typedef unsigned long long u64;
#define MFMA(a, b, c) __builtin_amdgcn_mfma_f32_16x16x32_bf16((a), (b), (c), 0, 0, 0)

// ---- bf16 helpers (RNE) ----
__device__ __forceinline__ short f2b(float f) {
    union { float f; unsigned u; } v; v.f = f;
    unsigned r = v.u + 0x7fffu + ((v.u >> 16) & 1u);
    return (short)(r >> 16);
}
__device__ __forceinline__ float b2f(short s) {
    union { unsigned u; float f; } v; v.u = ((unsigned)(unsigned short)s) << 16;
    return v.f;
}

// ===========================================================================
// prep: once per launch. bf16 weight transposes; hp = b_proj (h0=0);
// hinT (padded stride NNP) from x[:,0], m[:,0].
// ===========================================================================
__global__ __launch_bounds__(256) void prep_kernel(
    const float* __restrict__ x_seq, const float* __restrict__ m_seq,
    const float* __restrict__ W_in,  const float* __restrict__ b_in,
    const float* __restrict__ W_proj,const float* __restrict__ b_proj,
    const float* __restrict__ W_gcn,
    short* __restrict__ hp, short* __restrict__ hinT,
    short* __restrict__ WgT, short* __restrict__ WpT)
{
    const int b = blockIdx.x, tid = threadIdx.x;
    if (b < 256) {
        const int n0 = b * 16;
        for (int i = tid; i < 16 * HH; i += 256) {
            const int q = i >> 7, j = i & 127, n = n0 + q;
            hp[n * HH + j] = f2b(b_proj[j]);
            float hi = x_seq[n * TT] * W_in[j] + m_seq[n * TT] * W_in[HH + j] + b_in[j];
            hi = hi > 0.f ? hi : 0.f;
            hinT[(size_t)j * NNP + n] = f2b(hi);
        }
    } else {
        const int wb = b - 256;
        #pragma unroll
        for (int k = 0; k < 4; ++k) {
            const int idx = wb * 1024 + k * 256 + tid;   // = n*128 + kk
            const int n = idx >> 7, kk = idx & 127;
            WgT[idx] = f2b(W_gcn[kk * HH + n]);
            WpT[idx] = f2b(W_proj[kk * HH + n]);
        }
    }
}

// ===========================================================================
// Phase A: attention partials. 256 blocks (32 qg x 8 splits) x 512 thr
// (8 waves). Wave w owns q rows [qg*128 + 16w, +16); ALL waves share the
// block's 512-key slice via LDS-staged K/V tiles (double-buffered; the two
// barriers per tile also serialize the per-wave Pt round-trip -> no extra
// fences needed, R4-proven). Fixed-shift softmax; per-(split,q) partial
// O (fp32) and l go to Opart/lpart; kernel boundary publishes them.
// Traffic: K/V 256 KB/block (vs 2 MB in the R8 single-kernel design).
// ===========================================================================
__global__ __launch_bounds__(512, 2) void attn_kernel(
    const short* __restrict__ hp, const short* __restrict__ hinT,
    float* __restrict__ Opart, float* __restrict__ lpart)
{
    __shared__ __align__(16) short Kt[2][32 * 136];   // keys x d (pad 8)
    __shared__ __align__(16) short Vt[2][128 * 40];   // d x keys (pad 8)
    __shared__ __align__(16) short Pt[8][16 * 40];    // per-wave P transpose

    const int tid  = threadIdx.x;
    const int wave = tid >> 6, lane = tid & 63;
    const int ln = lane & 15, g = lane >> 4;
    const int qg = blockIdx.x >> 3, split = blockIdx.x & 7;
    const int q0 = qg * 128 + wave * 16;
    const int kbase = split * KPB;

    // staging thread maps (512 threads, fully coalesced 16B/lane)
    const int krow = tid >> 4, kcol = (tid & 15) * 8;   // 32 rows x 128 shorts
    const int vrow = tid >> 2, vcol = (tid & 3) * 8;    // 128 rows x 32 shorts

    // Q fragments (A-layout: 8 contiguous bf16 per lane)
    short8 qf[4];
    #pragma unroll
    for (int kc = 0; kc < 4; ++kc)
        qf[kc] = *(const short8*)&hp[(q0 + ln) * HH + kc * 32 + g * 8];

    f32x4 oacc[8] = {};
    float lsum[4] = {0.f, 0.f, 0.f, 0.f};

    short8 ksA, vsA;
    auto load_tile = [&](int kt_) {
        const int kb = kbase + kt_ * KT;
        ksA = *(const short8*)&hp  [(kb + krow) * HH + kcol];
        vsA = *(const short8*)&hinT[(size_t)vrow * NNP + kb + vcol];
    };
    auto store_tile = [&](int b) {
        *(short8*)&Kt[b][krow * 136 + kcol] = ksA;
        *(short8*)&Vt[b][vrow * 40 + vcol]  = vsA;
    };

    load_tile(0);
    store_tile(0);

    for (int kt = 0; kt < NTILES; ++kt) {
        const int b = kt & 1;
        __syncthreads();   // buf b staged; prev iter's Pt/frag reads done (WAR)

        short8 kf[2][4], vf[8];
        #pragma unroll
        for (int nt = 0; nt < 2; ++nt)
            #pragma unroll
            for (int kc = 0; kc < 4; ++kc)
                kf[nt][kc] = *(const short8*)&Kt[b][(nt * 16 + ln) * 136 + kc * 32 + g * 8];
        #pragma unroll
        for (int dt = 0; dt < 8; ++dt)
            vf[dt] = *(const short8*)&Vt[b][(dt * 16 + ln) * 40 + g * 8];

        if (kt + 1 < NTILES) load_tile(kt + 1);   // global -> regs, overlaps compute

        // scores S[16 x 32]
        f32x4 sacc[2] = {};
        #pragma unroll
        for (int nt = 0; nt < 2; ++nt)
            #pragma unroll
            for (int kc = 0; kc < 4; ++kc)
                sacc[nt] = MFMA(qf[kc], kf[nt][kc], sacc[nt]);

        // fixed-shift softmax numerators -> Pt; l sums rounded p
        #pragma unroll
        for (int nt = 0; nt < 2; ++nt)
            #pragma unroll
            for (int r = 0; r < 4; ++r) {
                const float p = __expf(sacc[nt][r] * SCALE - CSHIFT);
                const short pb = f2b(p);
                lsum[r] += b2f(pb);
                Pt[wave][(g * 4 + r) * 40 + nt * 16 + ln] = pb;
            }

        if (kt + 1 < NTILES) store_tile(b ^ 1);

        __syncthreads();   // Pt RAW fence + next buf fully staged

        short8 pf = *(const short8*)&Pt[wave][ln * 40 + g * 8];

        #pragma unroll
        for (int dt = 0; dt < 8; ++dt)
            oacc[dt] = MFMA(pf, vf[dt], oacc[dt]);
    }

    // l reduction over the 16-lane key dim; partial writes
    #pragma unroll
    for (int r = 0; r < 4; ++r) {
        float l = lsum[r];
        l += __shfl_xor(l, 1); l += __shfl_xor(l, 2);
        l += __shfl_xor(l, 4); l += __shfl_xor(l, 8);
        if (ln == 0) lpart[split * NN + q0 + g * 4 + r] = l;
    }
    #pragma unroll
    for (int dt = 0; dt < 8; ++dt)
        #pragma unroll
        for (int r = 0; r < 4; ++r)
            Opart[((size_t)split * NN + q0 + g * 4 + r) * HH + dt * 16 + ln] = oacc[dt][r];
}

// ===========================================================================
// Phase B: merge 8 partials -> msg; h_new = relu(msg@Wg + b_gcn + h_in(t));
// pred -> out[:,t]; h_proj(t+1) -> hp; h_in(t+1) -> hinT. h_in is recomputed
// in-kernel (bf16-rounding parity) — no hin array. 256 blocks x 256 thr.
// ===========================================================================
__global__ __launch_bounds__(256) void fuse_kernel(
    const float* __restrict__ Opart, const float* __restrict__ lpart,
    short* __restrict__ hp, short* __restrict__ hinT,
    const short* __restrict__ WgT, const short* __restrict__ WpT,
    const float* __restrict__ b_gcn, const float* __restrict__ b_proj,
    const float* __restrict__ W_out, const float* __restrict__ b_out,
    const float* __restrict__ x_seq, const float* __restrict__ m_seq,
    const float* __restrict__ W_in,  const float* __restrict__ b_in,
    float* __restrict__ out, int t)
{
    __shared__ __align__(16) short msgb[16 * 136];
    __shared__ __align__(16) short hnb[16 * 136];
    __shared__ __align__(16) short hintb[128 * 16];
    __shared__ float larr[16];
    __shared__ float ppd[4 * 16];

    const int tid = threadIdx.x;
    const int wave = tid >> 6, lane = tid & 63;
    const int ln = lane & 15, g = lane >> 4;
    const int qb = blockIdx.x * 16;

    if (tid < 16) {
        float l = 0.f;
        #pragma unroll
        for (int sp = 0; sp < SPLITS; ++sp) l += lpart[sp * NN + qb + tid];
        larr[tid] = 1.0f / l;
    }
    __syncthreads();

    // merge 8 partials -> msg (f32x4 coalesced reads, bf16 to LDS)
    for (int i = tid; i < 16 * 32; i += 256) {
        const int q = i >> 5, d4 = (i & 31) * 4;
        f32x4 s = {};
        #pragma unroll
        for (int sp = 0; sp < SPLITS; ++sp)
            s += *(const f32x4*)&Opart[((size_t)sp * NN + qb + q) * HH + d4];
        const float inv = larr[q];
        short* mp = &msgb[q * 136 + d4];
        mp[0] = f2b(s[0] * inv); mp[1] = f2b(s[1] * inv);
        mp[2] = f2b(s[2] * inv); mp[3] = f2b(s[3] * inv);
    }
    __syncthreads();

    // GEMM1: h_new = relu(msg @ W_gcn + b_gcn + h_in(t)); pred partials
    short8 af[4];
    #pragma unroll
    for (int kc = 0; kc < 4; ++kc)
        af[kc] = *(const short8*)&msgb[ln * 136 + kc * 32 + g * 8];
    float pr[4] = {0.f, 0.f, 0.f, 0.f};
    #pragma unroll
    for (int ni = 0; ni < 2; ++ni) {
        const int nt = wave * 2 + ni;
        f32x4 c = {};
        #pragma unroll
        for (int kc = 0; kc < 4; ++kc)
            c = MFMA(af[kc], *(const short8*)&WgT[(nt * 16 + ln) * HH + kc * 32 + g * 8], c);
        const int j = nt * 16 + ln;
        const float bg = b_gcn[j], wo = W_out[j];
        const float wj0 = W_in[j], wj1 = W_in[HH + j], bj = b_in[j];
        #pragma unroll
        for (int r = 0; r < 4; ++r) {
            const int q = g * 4 + r;
            float hi = x_seq[(qb + q) * TT + t] * wj0 + m_seq[(qb + q) * TT + t] * wj1 + bj;
            hi = hi > 0.f ? hi : 0.f;
            float v = c[r] + bg + b2f(f2b(hi));
            v = v > 0.f ? v : 0.f;
            hnb[q * 136 + j] = f2b(v);
            pr[r] += v * wo;
        }
    }
    #pragma unroll
    for (int r = 0; r < 4; ++r) {
        float p = pr[r];
        p += __shfl_xor(p, 1); p += __shfl_xor(p, 2);
        p += __shfl_xor(p, 4); p += __shfl_xor(p, 8);
        if (ln == 0) ppd[wave * 16 + g * 4 + r] = p;
    }
    __syncthreads();   // hnb + ppd complete

    if (tid < 16)
        out[(qb + tid) * TT + t] = ppd[tid] + ppd[16 + tid] + ppd[32 + tid] + ppd[48 + tid] + b_out[0];

    if (t < TT - 1) {
        // GEMM2: h_proj(t+1) = h_new @ W_proj + b_proj -> hp (read next launch)
        short8 hf[4];
        #pragma unroll
        for (int kc = 0; kc < 4; ++kc)
            hf[kc] = *(const short8*)&hnb[ln * 136 + kc * 32 + g * 8];
        #pragma unroll
        for (int ni = 0; ni < 2; ++ni) {
            const int nt = wave * 2 + ni;
            f32x4 c = {};
            #pragma unroll
            for (int kc = 0; kc < 4; ++kc)
                c = MFMA(hf[kc], *(const short8*)&WpT[(nt * 16 + ln) * HH + kc * 32 + g * 8], c);
            const float bp = b_proj[nt * 16 + ln];
            #pragma unroll
            for (int r = 0; r < 4; ++r)
                hp[(qb + g * 4 + r) * HH + nt * 16 + ln] = f2b(c[r] + bp);
        }

        // h_in(t+1): LDS transpose then 8B-chunk stores into padded hinT
        for (int i = tid; i < 16 * HH; i += 256) {
            const int q = i >> 7, j = i & 127;
            float hi = x_seq[(qb + q) * TT + t + 1] * W_in[j]
                     + m_seq[(qb + q) * TT + t + 1] * W_in[HH + j] + b_in[j];
            hi = hi > 0.f ? hi : 0.f;
            hintb[j * 16 + q] = f2b(hi);
        }
        __syncthreads();
        for (int c = tid; c < 512; c += 256) {
            const int j = c >> 2, off = (c & 3) * 4;
            *(u64*)&hinT[(size_t)j * NNP + qb + off] = *(const u64*)&hintb[j * 16 + off];
        }
    }
}

// ===========================================================================
extern "C" void kernel_launch(void* const* d_in, const int* in_sizes, int n_in,
                              void* d_out, int out_size, void* d_ws, size_t ws_size,
                              hipStream_t stream) {
    const float* x_seq  = (const float*)d_in[0];
    const float* m_seq  = (const float*)d_in[1];
    const float* W_in   = (const float*)d_in[2];
    const float* b_in   = (const float*)d_in[3];
    const float* W_proj = (const float*)d_in[4];
    const float* b_proj = (const float*)d_in[5];
    const float* W_gcn  = (const float*)d_in[6];
    const float* b_gcn  = (const float*)d_in[7];
    const float* W_out  = (const float*)d_in[8];
    const float* b_out  = (const float*)d_in[9];
    float* out = (float*)d_out;

    // ws carve (~20 MB): hp | hinT(padded) | WgT | WpT | lpart | Opart
    char* base = (char*)d_ws;
    const size_t MB = 1 << 20;
    short* hp    = (short*)(base + 0 * MB);
    short* hinT  = (short*)(base + 1 * MB);           // 128*4160*2 B = 1.04 MB
    short* WgT   = (short*)(base + 3 * MB);
    short* WpT   = (short*)(base + 3 * MB + 32768);
    float* lpart = (float*)(base + 3 * MB + 65536);   // 8*4096*4 = 128 KB
    float* Opart = (float*)(base + 4 * MB);           // 8*4096*128*4 = 16 MB

    prep_kernel<<<272, 256, 0, stream>>>(x_seq, m_seq, W_in, b_in, W_proj, b_proj,
                                         W_gcn, hp, hinT, WgT, WpT);

    for (int t = 0; t < TT; ++t) {
        attn_kernel<<<(NN / 128) * SPLITS, 512, 0, stream>>>(hp, hinT, Opart, lpart);
        fuse_kernel<<<NN / 16, 256, 0, stream>>>(Opart, lpart, hp, hinT,
                                                 WgT, WpT, b_gcn, b_proj, W_out, b_out,
                                                 x_seq, m_seq, W_in, b_in, out, t);
    }
}

// Round 10
// 2183.712 us; speedup vs baseline: 8.4959x; 1.2027x over previous
//
#include <hip/hip_runtime.h>
#include <math.h>

#define NN 4096
#define TT 64
#define HH 128
#define NNP 4160            // hinT row stride (shorts): 8320B kills 8KB L2 set-aliasing
#define SPLITS 16
#define KPB (NN / SPLITS)   // 256 keys per phase-A block
#define KT 32
#define NTILES (KPB / KT)   // 8
#define SCALE 0.08838834764831845f   // 1/sqrt(128)
#define CSHIFT 16.0f

typedef __attribute__((ext_vector_type(8))) short short8;
typedef __attribute__((ext_vector_type(4))) float f32x4;
typedef unsigned long long u64;
#define MFMA(a, b, c) __builtin_amdgcn_mfma_f32_16x16x32_bf16((a), (b), (c), 0, 0, 0)

// ---- bf16 helpers (RNE) ----
__device__ __forceinline__ short f2b(float f) {
    union { float f; unsigned u; } v; v.f = f;
    unsigned r = v.u + 0x7fffu + ((v.u >> 16) & 1u);
    return (short)(r >> 16);
}
__device__ __forceinline__ float b2f(short s) {
    union { unsigned u; float f; } v; v.u = ((unsigned)(unsigned short)s) << 16;
    return v.f;
}
// Wave-local LDS fence (R7/R8-proven): completes ds ops + blocks compiler
// reordering of cross-lane LDS accesses without a block barrier.
__device__ __forceinline__ void lds_fence() {
    __asm__ __volatile__("s_waitcnt lgkmcnt(0)" ::: "memory");
}

// ===========================================================================
// prep: once per launch. bf16 weight transposes; hp = b_proj (h0=0);
// hinT (padded stride NNP) from x[:,0], m[:,0].
// ===========================================================================
__global__ __launch_bounds__(256) void prep_kernel(
    const float* __restrict__ x_seq, const float* __restrict__ m_seq,
    const float* __restrict__ W_in,  const float* __restrict__ b_in,
    const float* __restrict__ W_proj,const float* __restrict__ b_proj,
    const float* __restrict__ W_gcn,
    short* __restrict__ hp, short* __restrict__ hinT,
    short* __restrict__ WgT, short* __restrict__ WpT)
{
    const int b = blockIdx.x, tid = threadIdx.x;
    if (b < 256) {
        const int n0 = b * 16;
        for (int i = tid; i < 16 * HH; i += 256) {
            const int q = i >> 7, j = i & 127, n = n0 + q;
            hp[n * HH + j] = f2b(b_proj[j]);
            float hi = x_seq[n * TT] * W_in[j] + m_seq[n * TT] * W_in[HH + j] + b_in[j];
            hi = hi > 0.f ? hi : 0.f;
            hinT[(size_t)j * NNP + n] = f2b(hi);
        }
    } else {
        const int wb = b - 256;
        #pragma unroll
        for (int k = 0; k < 4; ++k) {
            const int idx = wb * 1024 + k * 256 + tid;   // = n*128 + kk
            const int n = idx >> 7, kk = idx & 127;
            WgT[idx] = f2b(W_gcn[kk * HH + n]);
            WpT[idx] = f2b(W_proj[kk * HH + n]);
        }
    }
}

// ===========================================================================
// Phase A: attention partials. 256 blocks (16 qg x 16 splits) x 512 thr
// (8 waves). Wave w owns 32 q rows [qg*256+32w, +32) (2 m-tiles); all waves
// share the block's 256-key slice via LDS-staged double-buffered K/V tiles
// (2 barriers/tile serialize the per-wave Pt round-trip too — R4-proven).
// QB=KPB=256 is the traffic-optimal 256-block tiling: K/V 32 MB/step.
// Partial O is written as bf16 through a per-wave LDS bounce (coalesced
// 16B/lane stores); l stays fp32. Kernel boundary publishes state.
// ===========================================================================
__global__ __launch_bounds__(512, 2) void attn_kernel(
    const short* __restrict__ hp, const short* __restrict__ hinT,
    short* __restrict__ OpartB, float* __restrict__ lpart)
{
    __shared__ __align__(16) char pool[58368];
    short* KtS = (short*)pool;                  // [2][32*136]  17408 B
    short* VtS = (short*)(pool + 17408);        // [2][128*40]  20480 B
    short* PtS = (short*)(pool + 37888);        // [8][32*40]   20480 B

    const int tid  = threadIdx.x;
    const int wave = tid >> 6, lane = tid & 63;
    const int ln = lane & 15, g = lane >> 4;
    const int qg = blockIdx.x >> 4, split = blockIdx.x & 15;
    const int q0 = qg * 256 + wave * 32;
    const int kbase = split * KPB;

    // staging thread maps (512 threads, 16B/lane coalesced)
    const int krow = tid >> 4, kcol = (tid & 15) * 8;   // 32 rows x 128 shorts
    const int vrow = tid >> 2, vcol = (tid & 3) * 8;    // 128 rows x 32 shorts

    // Q fragments: 2 m-tiles (A-layout: 8 contiguous bf16/lane)
    short8 qf[2][4];
    #pragma unroll
    for (int mt = 0; mt < 2; ++mt)
        #pragma unroll
        for (int kc = 0; kc < 4; ++kc)
            qf[mt][kc] = *(const short8*)&hp[(q0 + mt * 16 + ln) * HH + kc * 32 + g * 8];

    f32x4 oacc[2][8] = {};
    float lsum[2][4] = {};

    short8 ksA, vsA;
    auto load_tile = [&](int kt_) {
        const int kb = kbase + kt_ * KT;
        ksA = *(const short8*)&hp  [(kb + krow) * HH + kcol];
        vsA = *(const short8*)&hinT[(size_t)vrow * NNP + kb + vcol];
    };
    auto store_tile = [&](int b) {
        *(short8*)&KtS[b * 4352 + krow * 136 + kcol] = ksA;
        *(short8*)&VtS[b * 5120 + vrow * 40 + vcol]  = vsA;
    };

    load_tile(0);
    store_tile(0);

    for (int kt = 0; kt < NTILES; ++kt) {
        const int b = kt & 1;
        __syncthreads();   // buf b staged; prev iter's Pt/frag reads done (WAR)

        short8 kf[2][4], vf[8];
        #pragma unroll
        for (int nt = 0; nt < 2; ++nt)
            #pragma unroll
            for (int kc = 0; kc < 4; ++kc)
                kf[nt][kc] = *(const short8*)&KtS[b * 4352 + (nt * 16 + ln) * 136 + kc * 32 + g * 8];
        #pragma unroll
        for (int dt = 0; dt < 8; ++dt)
            vf[dt] = *(const short8*)&VtS[b * 5120 + (dt * 16 + ln) * 40 + g * 8];

        if (kt + 1 < NTILES) load_tile(kt + 1);   // global -> regs, overlaps compute

        // scores S[32 x 32]
        f32x4 sacc[2][2] = {};
        #pragma unroll
        for (int mt = 0; mt < 2; ++mt)
            #pragma unroll
            for (int nt = 0; nt < 2; ++nt)
                #pragma unroll
                for (int kc = 0; kc < 4; ++kc)
                    sacc[mt][nt] = MFMA(qf[mt][kc], kf[nt][kc], sacc[mt][nt]);

        // fixed-shift softmax numerators -> Pt; l sums rounded p
        #pragma unroll
        for (int mt = 0; mt < 2; ++mt)
            #pragma unroll
            for (int nt = 0; nt < 2; ++nt)
                #pragma unroll
                for (int r = 0; r < 4; ++r) {
                    const float p = __expf(sacc[mt][nt][r] * SCALE - CSHIFT);
                    const short pb = f2b(p);
                    lsum[mt][r] += b2f(pb);
                    PtS[wave * 1280 + (mt * 16 + g * 4 + r) * 40 + nt * 16 + ln] = pb;
                }

        if (kt + 1 < NTILES) store_tile(b ^ 1);

        __syncthreads();   // Pt RAW fence + next buf fully staged

        short8 pf0 = *(const short8*)&PtS[wave * 1280 + ln * 40 + g * 8];
        short8 pf1 = *(const short8*)&PtS[wave * 1280 + (16 + ln) * 40 + g * 8];

        #pragma unroll
        for (int dt = 0; dt < 8; ++dt) {
            oacc[0][dt] = MFMA(pf0, vf[dt], oacc[0][dt]);
            oacc[1][dt] = MFMA(pf1, vf[dt], oacc[1][dt]);
        }
    }
    // After the loop Kt/Vt are dead for ALL waves (frag reads precede the
    // final 2nd barrier) -> safe to reuse as per-wave bounce, no extra sync.

    // l reduction over the 16-lane key dim
    #pragma unroll
    for (int mt = 0; mt < 2; ++mt)
        #pragma unroll
        for (int r = 0; r < 4; ++r) {
            float l = lsum[mt][r];
            l += __shfl_xor(l, 1); l += __shfl_xor(l, 2);
            l += __shfl_xor(l, 4); l += __shfl_xor(l, 8);
            if (ln == 0) lpart[split * NN + q0 + mt * 16 + g * 4 + r] = l;
        }

    // O partials -> bf16 via per-wave LDS bounce (coalesced 16B/lane stores)
    short* bounce = (short*)pool + wave * 2048;   // 4KB/wave in dead Kt/Vt
    #pragma unroll
    for (int mt = 0; mt < 2; ++mt) {
        #pragma unroll
        for (int dt = 0; dt < 8; ++dt)
            #pragma unroll
            for (int r = 0; r < 4; ++r)
                bounce[(g * 4 + r) * 128 + dt * 16 + ln] = f2b(oacc[mt][dt][r]);
        lds_fence();   // RAW: cross-lane bounce writes before row reads
        #pragma unroll
        for (int sub = 0; sub < 4; ++sub) {
            const int qrow = sub * 4 + (lane >> 4), chunk = lane & 15;
            const short8 rd = *(const short8*)&bounce[qrow * 128 + chunk * 8];
            *(short8*)&OpartB[((size_t)split * NN + q0 + mt * 16 + qrow) * HH + chunk * 8] = rd;
        }
        lds_fence();   // WAR before next mt overwrites the bounce
    }
}

// ===========================================================================
// Phase B: merge 16 bf16 partials -> msg; h_new = relu(msg@Wg+b_gcn+h_in(t));
// pred -> out[:,t]; h_proj(t+1) -> hp; h_in(t+1) -> hinT (recomputed, bf16-
// rounding parity). 256 blocks x 256 thr.
// ===========================================================================
__global__ __launch_bounds__(256) void fuse_kernel(
    const short* __restrict__ OpartB, const float* __restrict__ lpart,
    short* __restrict__ hp, short* __restrict__ hinT,
    const short* __restrict__ WgT, const short* __restrict__ WpT,
    const float* __restrict__ b_gcn, const float* __restrict__ b_proj,
    const float* __restrict__ W_out, const float* __restrict__ b_out,
    const float* __restrict__ x_seq, const float* __restrict__ m_seq,
    const float* __restrict__ W_in,  const float* __restrict__ b_in,
    float* __restrict__ out, int t)
{
    __shared__ __align__(16) short msgb[16 * 136];
    __shared__ __align__(16) short hnb[16 * 136];
    __shared__ __align__(16) short hintb[128 * 16];
    __shared__ float larr[16];
    __shared__ float ppd[4 * 16];

    const int tid = threadIdx.x;
    const int wave = tid >> 6, lane = tid & 63;
    const int ln = lane & 15, g = lane >> 4;
    const int qb = blockIdx.x * 16;

    if (tid < 16) {
        float l = 0.f;
        #pragma unroll
        for (int sp = 0; sp < SPLITS; ++sp) l += lpart[sp * NN + qb + tid];
        larr[tid] = 1.0f / l;
    }
    __syncthreads();

    // merge 16 bf16 partials -> msg (short8 coalesced reads, fp32 accumulate)
    {
        const int q = tid >> 4, c8 = (tid & 15) * 8;   // 256 thr = 16q x 16 chunks
        float s[8] = {0.f, 0.f, 0.f, 0.f, 0.f, 0.f, 0.f, 0.f};
        #pragma unroll
        for (int sp = 0; sp < SPLITS; ++sp) {
            const short8 v = *(const short8*)&OpartB[((size_t)sp * NN + qb + q) * HH + c8];
            #pragma unroll
            for (int k = 0; k < 8; ++k) s[k] += b2f(v[k]);
        }
        const float inv = larr[q];
        short* mp = &msgb[q * 136 + c8];
        #pragma unroll
        for (int k = 0; k < 8; ++k) mp[k] = f2b(s[k] * inv);
    }
    __syncthreads();

    // GEMM1: h_new = relu(msg @ W_gcn + b_gcn + h_in(t)); pred partials
    short8 af[4];
    #pragma unroll
    for (int kc = 0; kc < 4; ++kc)
        af[kc] = *(const short8*)&msgb[ln * 136 + kc * 32 + g * 8];
    float pr[4] = {0.f, 0.f, 0.f, 0.f};
    #pragma unroll
    for (int ni = 0; ni < 2; ++ni) {
        const int nt = wave * 2 + ni;
        f32x4 c = {};
        #pragma unroll
        for (int kc = 0; kc < 4; ++kc)
            c = MFMA(af[kc], *(const short8*)&WgT[(nt * 16 + ln) * HH + kc * 32 + g * 8], c);
        const int j = nt * 16 + ln;
        const float bg = b_gcn[j], wo = W_out[j];
        const float wj0 = W_in[j], wj1 = W_in[HH + j], bj = b_in[j];
        #pragma unroll
        for (int r = 0; r < 4; ++r) {
            const int q = g * 4 + r;
            float hi = x_seq[(qb + q) * TT + t] * wj0 + m_seq[(qb + q) * TT + t] * wj1 + bj;
            hi = hi > 0.f ? hi : 0.f;
            float v = c[r] + bg + b2f(f2b(hi));
            v = v > 0.f ? v : 0.f;
            hnb[q * 136 + j] = f2b(v);
            pr[r] += v * wo;
        }
    }
    #pragma unroll
    for (int r = 0; r < 4; ++r) {
        float p = pr[r];
        p += __shfl_xor(p, 1); p += __shfl_xor(p, 2);
        p += __shfl_xor(p, 4); p += __shfl_xor(p, 8);
        if (ln == 0) ppd[wave * 16 + g * 4 + r] = p;
    }
    __syncthreads();   // hnb + ppd complete

    if (tid < 16)
        out[(qb + tid) * TT + t] = ppd[tid] + ppd[16 + tid] + ppd[32 + tid] + ppd[48 + tid] + b_out[0];

    if (t < TT - 1) {
        // GEMM2: h_proj(t+1) = h_new @ W_proj + b_proj -> hp
        short8 hf[4];
        #pragma unroll
        for (int kc = 0; kc < 4; ++kc)
            hf[kc] = *(const short8*)&hnb[ln * 136 + kc * 32 + g * 8];
        #pragma unroll
        for (int ni = 0; ni < 2; ++ni) {
            const int nt = wave * 2 + ni;
            f32x4 c = {};
            #pragma unroll
            for (int kc = 0; kc < 4; ++kc)
                c = MFMA(hf[kc], *(const short8*)&WpT[(nt * 16 + ln) * HH + kc * 32 + g * 8], c);
            const float bp = b_proj[nt * 16 + ln];
            #pragma unroll
            for (int r = 0; r < 4; ++r)
                hp[(qb + g * 4 + r) * HH + nt * 16 + ln] = f2b(c[r] + bp);
        }

        // h_in(t+1): LDS transpose then 8B-chunk stores into padded hinT
        for (int i = tid; i < 16 * HH; i += 256) {
            const int q = i >> 7, j = i & 127;
            float hi = x_seq[(qb + q) * TT + t + 1] * W_in[j]
                     + m_seq[(qb + q) * TT + t + 1] * W_in[HH + j] + b_in[j];
            hi = hi > 0.f ? hi : 0.f;
            hintb[j * 16 + q] = f2b(hi);
        }
        __syncthreads();
        for (int c = tid; c < 512; c += 256) {
            const int j = c >> 2, off = (c & 3) * 4;
            *(u64*)&hinT[(size_t)j * NNP + qb + off] = *(const u64*)&hintb[j * 16 + off];
        }
    }
}

// ===========================================================================
extern "C" void kernel_launch(void* const* d_in, const int* in_sizes, int n_in,
                              void* d_out, int out_size, void* d_ws, size_t ws_size,
                              hipStream_t stream) {
    const float* x_seq  = (const float*)d_in[0];
    const float* m_seq  = (const float*)d_in[1];
    const float* W_in   = (const float*)d_in[2];
    const float* b_in   = (const float*)d_in[3];
    const float* W_proj = (const float*)d_in[4];
    const float* b_proj = (const float*)d_in[5];
    const float* W_gcn  = (const float*)d_in[6];
    const float* b_gcn  = (const float*)d_in[7];
    const float* W_out  = (const float*)d_in[8];
    const float* b_out  = (const float*)d_in[9];
    float* out = (float*)d_out;

    // ws carve (~20 MB): hp | hinT(padded) | WgT | WpT | lpart | OpartB
    char* base = (char*)d_ws;
    const size_t MB = 1 << 20;
    short* hp     = (short*)(base + 0 * MB);
    short* hinT   = (short*)(base + 1 * MB);           // 128*4160*2 B
    short* WgT    = (short*)(base + 3 * MB);
    short* WpT    = (short*)(base + 3 * MB + 32768);
    float* lpart  = (float*)(base + 3 * MB + 65536);   // 16*4096*4 = 256 KB
    short* OpartB = (short*)(base + 4 * MB);           // 16*4096*128*2 = 16 MB

    prep_kernel<<<272, 256, 0, stream>>>(x_seq, m_seq, W_in, b_in, W_proj, b_proj,
                                         W_gcn, hp, hinT, WgT, WpT);

    for (int t = 0; t < TT; ++t) {
        attn_kernel<<<(NN / 256) * SPLITS, 512, 0, stream>>>(hp, hinT, OpartB, lpart);
        fuse_kernel<<<NN / 16, 256, 0, stream>>>(OpartB, lpart, hp, hinT,
                                                 WgT, WpT, b_gcn, b_proj, W_out, b_out,
                                                 x_seq, m_seq, W_in, b_in, out, t);
    }
}